// Round 1
// baseline (3901.867 us; speedup 1.0000x reference)
//
#include <hip/hip_runtime.h>
#include <math.h>

#define NCLS 80
#define PRE_NMS_K 400
#define MAX_BOXES 200
#define KEEP_CAP 200
#define N_TOT 16128
#define SORT_N 16384
#define NMS_T 0.6f
#define NTHR 256

__device__ __forceinline__ float sigf(float x) { return 1.0f / (1.0f + expf(-x)); }

// descending bitonic sort of SORT_N u64 keys in LDS
__device__ __forceinline__ void bitonic_sort_desc(unsigned long long* keys, int tid) {
    for (int k = 2; k <= SORT_N; k <<= 1) {
        for (int j = k >> 1; j > 0; j >>= 1) {
            for (int i = tid; i < SORT_N; i += NTHR) {
                int ixj = i ^ j;
                if (ixj > i) {
                    unsigned long long va = keys[i], vb = keys[ixj];
                    bool desc = ((i & k) == 0);
                    bool sw = desc ? (va < vb) : (va > vb);
                    if (sw) { keys[i] = vb; keys[ixj] = va; }
                }
            }
            __syncthreads();
        }
    }
}

// ---- Kernel 2: per (image, class): top-400 -> greedy NMS -> compact kept (<=200)
__global__ __launch_bounds__(NTHR) void topk_nms_kernel(
    const float* __restrict__ p3, const float* __restrict__ p4, const float* __restrict__ p5,
    const float* __restrict__ a3, const float* __restrict__ a4, const float* __restrict__ a5,
    float* __restrict__ ksc, float* __restrict__ kbox)
{
    __shared__ unsigned long long keys[SORT_N];   // 128 KiB
    __shared__ float sc[PRE_NMS_K];
    __shared__ float bx[PRE_NMS_K][4];
    __shared__ int   keepf[PRE_NMS_K];
    __shared__ short posar[PRE_NMS_K];
    __shared__ int   ncnt;

    const int tid = threadIdx.x;
    const int blk = blockIdx.x;
    const int b = blk / NCLS;
    const int c = blk % NCLS;

    // ---- fill keys with (score_bits, ~idx)
    for (int i = tid; i < SORT_N; i += NTHR) {
        unsigned long long key = 0ull;
        if (i < N_TOT) {
            const float* base; int H, W, n;
            if (i < 12288)      { base = p3; H = 64; W = 64; n = i; }
            else if (i < 15360) { base = p4; H = 32; W = 32; n = i - 12288; }
            else                { base = p5; H = 16; W = 16; n = i - 15360; }
            int a = n % 3; int hw = n / 3; int w = hw % W; int h = hw / W;
            const float* rec = base + (((long)(b * H + h) * W + w) * 255 + a * 85);
            float obj = sigf(rec[4]);
            float cl  = sigf(rec[5 + c]);
            float s = cl * obj;   // masks in reference are all-ones (sigmoid > 0)
            key = ((unsigned long long)__float_as_uint(s) << 32)
                | (unsigned int)(0xFFFFFFFFu - (unsigned)i);
        }
        keys[i] = key;
    }
    __syncthreads();

    bitonic_sort_desc(keys, tid);

    // ---- gather top-400, decode + clip boxes
    for (int t = tid; t < PRE_NMS_K; t += NTHR) {
        unsigned long long key = keys[t];
        float s = __uint_as_float((unsigned int)(key >> 32));
        sc[t] = s;
        keepf[t] = 1;
        float y1 = 0.f, x1 = 0.f, y2 = 0.f, x2 = 0.f;
        if (s > 0.0f) {
            int idx = (int)(0xFFFFFFFFu - (unsigned int)(key & 0xFFFFFFFFull));
            const float* base; const float* anc; int H, W, n; float sx, strd;
            if (idx < 12288)      { base = p3; anc = a3; H = 64; W = 64; n = idx;         sx = 1.2f;  strd = 8.f;  }
            else if (idx < 15360) { base = p4; anc = a4; H = 32; W = 32; n = idx - 12288; sx = 1.1f;  strd = 16.f; }
            else                  { base = p5; anc = a5; H = 16; W = 16; n = idx - 15360; sx = 1.05f; strd = 32.f; }
            int a = n % 3; int hw = n / 3; int w = hw % W; int h = hw / W;
            const float* rec = base + (((long)(b * H + h) * W + w) * 255 + a * 85);
            float tx = rec[0], ty = rec[1], tw = rec[2], th = rec[3];
            float cx = (sigf(tx) * sx - 0.5f * (sx - 1.0f) + (float)w) / (float)W;
            float cy = (sigf(ty) * sx - 0.5f * (sx - 1.0f) + (float)h) / (float)H;
            float bw = expf(tw) * anc[a * 2 + 0] / ((float)W * strd);
            float bh = expf(th) * anc[a * 2 + 1] / ((float)H * strd);
            x1 = cx - 0.5f * bw; x2 = cx + 0.5f * bw;
            y1 = cy - 0.5f * bh; y2 = cy + 0.5f * bh;
            y1 = fminf(fmaxf(y1, 0.f), 1.f); x1 = fminf(fmaxf(x1, 0.f), 1.f);
            y2 = fminf(fmaxf(y2, 0.f), 1.f); x2 = fminf(fmaxf(x2, 0.f), 1.f);
        }
        bx[t][0] = y1; bx[t][1] = x1; bx[t][2] = y2; bx[t][3] = x2;
    }
    __syncthreads();

    // ---- greedy NMS (sequential over i, parallel over j)
    for (int i = 0; i < PRE_NMS_K - 1; ++i) {
        if (keepf[i]) {
            float iy1 = bx[i][0], ix1 = bx[i][1], iy2 = bx[i][2], ix2 = bx[i][3];
            float ai = (iy2 - iy1) * (ix2 - ix1);
            for (int j = i + 1 + tid; j < PRE_NMS_K; j += NTHR) {
                if (keepf[j]) {
                    float jy1 = bx[j][0], jx1 = bx[j][1], jy2 = bx[j][2], jx2 = bx[j][3];
                    float ty = fmaxf(iy1, jy1);
                    float tx = fmaxf(ix1, jx1);
                    float by = fminf(iy2, jy2);
                    float rx = fminf(ix2, jx2);
                    float hh = fmaxf(by - ty, 0.f);
                    float ww = fmaxf(rx - tx, 0.f);
                    float inter = hh * ww;
                    float aj = (jy2 - jy1) * (jx2 - jx1);
                    float uni = ai + aj - inter;
                    float iou = inter / fmaxf(uni, 1e-9f);
                    if (iou > NMS_T) keepf[j] = 0;
                }
            }
        }
        __syncthreads();
    }

    // ---- compact kept entries (cap 200), zero-pad
    if (tid == 0) {
        int cnt = 0;
        for (int i = 0; i < PRE_NMS_K; ++i) {
            if (keepf[i] && sc[i] > 0.0f && cnt < KEEP_CAP) posar[i] = (short)cnt++;
            else posar[i] = -1;
        }
        ncnt = cnt;
    }
    __syncthreads();

    float* osc = ksc + (long)blk * KEEP_CAP;
    float* obx = kbox + (long)blk * KEEP_CAP * 4;
    for (int t = tid; t < PRE_NMS_K; t += NTHR) {
        int p = posar[t];
        if (p >= 0) {
            osc[p] = sc[t];
            obx[p * 4 + 0] = bx[t][0]; obx[p * 4 + 1] = bx[t][1];
            obx[p * 4 + 2] = bx[t][2]; obx[p * 4 + 3] = bx[t][3];
        }
    }
    for (int t = ncnt + tid; t < KEEP_CAP; t += NTHR) {
        osc[t] = 0.0f;
        obx[t * 4 + 0] = 0.f; obx[t * 4 + 1] = 0.f; obx[t * 4 + 2] = 0.f; obx[t * 4 + 3] = 0.f;
    }
}

// ---- Kernel 3: per image: top-200 over 80*200 compacted candidates -> outputs
__global__ __launch_bounds__(NTHR) void final_topk_kernel(
    const float* __restrict__ ksc, const float* __restrict__ kbox,
    float* __restrict__ out)
{
    __shared__ unsigned long long keys[SORT_N];   // 128 KiB
    const int tid = threadIdx.x;
    const int b = blockIdx.x;
    const int M = NCLS * KEEP_CAP;   // 16000

    for (int i = tid; i < SORT_N; i += NTHR) {
        unsigned long long key = 0ull;
        if (i < M) {
            float s = ksc[(long)b * M + i];
            if (s > 0.0f) {
                key = ((unsigned long long)__float_as_uint(s) << 32)
                    | (unsigned int)(0xFFFFFFFFu - (unsigned)i);
            }
        }
        keys[i] = key;
    }
    __syncthreads();

    bitonic_sort_desc(keys, tid);

    float* obb = out;                              // (8,200,4)
    float* ocf = out + 8 * MAX_BOXES * 4;          // (8,200)
    float* ocl = ocf + 8 * MAX_BOXES;              // (8,200)
    float* onm = ocl + 8 * MAX_BOXES;              // (8,)

    for (int t = tid; t < MAX_BOXES; t += NTHR) {
        unsigned long long key = keys[t];
        float s = __uint_as_float((unsigned int)(key >> 32));
        float y1 = 0.f, x1 = 0.f, y2 = 0.f, x2 = 0.f, cid = 0.f;
        if (s > 0.0f) {
            int i = (int)(0xFFFFFFFFu - (unsigned int)(key & 0xFFFFFFFFull));
            int c = i / KEEP_CAP; int j = i % KEEP_CAP;
            const float* bb = kbox + (((long)b * NCLS + c) * KEEP_CAP + j) * 4;
            y1 = bb[0]; x1 = bb[1]; y2 = bb[2]; x2 = bb[3];
            cid = (float)c;
        }
        long o = (long)b * MAX_BOXES + t;
        obb[o * 4 + 0] = y1; obb[o * 4 + 1] = x1; obb[o * 4 + 2] = y2; obb[o * 4 + 3] = x2;
        ocf[o] = s; ocl[o] = cid;
    }
    if (tid == 0) {
        int cnt = 0;
        for (int t = 0; t < MAX_BOXES; ++t) if ((keys[t] >> 32) != 0ull) ++cnt;
        onm[b] = (float)cnt;
    }
}

extern "C" void kernel_launch(void* const* d_in, const int* in_sizes, int n_in,
                              void* d_out, int out_size, void* d_ws, size_t ws_size,
                              hipStream_t stream) {
    const float* p3 = (const float*)d_in[0];
    const float* p4 = (const float*)d_in[1];
    const float* p5 = (const float*)d_in[2];
    const float* a3 = (const float*)d_in[3];
    const float* a4 = (const float*)d_in[4];
    const float* a5 = (const float*)d_in[5];
    float* out = (float*)d_out;

    // workspace: kept scores (8*80*200 f32) + kept boxes (8*80*200*4 f32) = 2.56 MB
    float* ksc  = (float*)d_ws;
    float* kbox = ksc + 8 * NCLS * KEEP_CAP;

    topk_nms_kernel<<<8 * NCLS, NTHR, 0, stream>>>(p3, p4, p5, a3, a4, a5, ksc, kbox);
    final_topk_kernel<<<8, NTHR, 0, stream>>>(ksc, kbox, out);
}

// Round 2
// 503.307 us; speedup vs baseline: 7.7525x; 7.7525x over previous
//
#include <hip/hip_runtime.h>
#include <math.h>

#define NCLS 80
#define PRE_K 400
#define MAX_BOXES 200
#define KEEP_CAP 200
#define N_TOT 16128
#define M_FIN (NCLS * KEEP_CAP)   // 16000
#define NMS_T 0.6f
#define NTHR 256
#define CHUNK2 63                  // N_TOT / NTHR exactly
#define CHUNK3 63                  // ceil(M_FIN / NTHR)

typedef unsigned long long u64;
typedef unsigned int u32;

__device__ __forceinline__ float sigf(float x) { return 1.0f / (1.0f + expf(-x)); }

// Exact descending top-K threshold select over n positive-float keys in LDS.
// Post: *p_thr = key value of the K-th element (32-bit), *p_need = how many
// elements equal to *p_thr must be taken (tie count to take, >=1).
// count(key > thr) + need == K.
__device__ void radix_select_desc(const u32* __restrict__ skey, int n, int K,
                                  u32* hist, u32* s0, u32* s1,
                                  u32* p_thr, int* p_need)
{
    const int tid = threadIdx.x;
    if (tid == 0) { *p_thr = 0u; *p_need = K; }
    __syncthreads();
    for (int shift = 24; shift >= 0; shift -= 8) {
        u32 prefix = *p_thr;
        int need = *p_need;
        hist[tid] = 0u;
        __syncthreads();
        for (int i = tid; i < n; i += NTHR) {
            u32 k = skey[i];
            bool match = (shift == 24) || ((k >> (shift + 8)) == prefix);
            if (match) atomicAdd(&hist[(k >> shift) & 255u], 1u);
        }
        __syncthreads();
        // inclusive suffix sum: cur[d] = count(digit >= d)
        s0[tid] = hist[tid];
        __syncthreads();
        u32* cur = s0; u32* oth = s1;
        for (int off = 1; off < 256; off <<= 1) {
            u32 v = cur[tid] + ((tid + off < 256) ? cur[tid + off] : 0u);
            oth[tid] = v;
            __syncthreads();
            u32* tmp = cur; cur = oth; oth = tmp;
        }
        u32 Sd = cur[tid];
        u32 Sd1 = (tid < 255) ? cur[tid + 1] : 0u;
        if ((int)Sd >= need && (int)Sd1 < need) {   // exactly one tid
            *p_thr = (prefix << 8) | (u32)tid;
            *p_need = need - (int)Sd1;
        }
        __syncthreads();
    }
}

// ---- Kernel A: per (image,class): radix top-400 -> sort 512 -> bitmask NMS -> compact
__global__ __launch_bounds__(NTHR) void topk_nms_kernel(
    const float* __restrict__ p3, const float* __restrict__ p4, const float* __restrict__ p5,
    const float* __restrict__ a3, const float* __restrict__ a4, const float* __restrict__ a5,
    float* __restrict__ ksc, float* __restrict__ kbox)
{
    __shared__ alignas(16) u32 skey[N_TOT];   // 64512 B; later overlaid: sup u64[2800] + box SoA
    __shared__ u64 cand[512];
    __shared__ u32 hist[256], sb0[256], sb1[256];
    __shared__ u32 sh_thr; __shared__ int sh_need, sh_gcnt;
    __shared__ u64 keepw[7];
    __shared__ int wpre[8];
    __shared__ int sh_ncnt;

    const int tid = threadIdx.x;
    const int b = blockIdx.x & 7;     // image -> same XCD for all its 80 class-blocks
    const int c = blockIdx.x >> 3;

    // ---- scores (2 scattered f32 reads + 2 sigmoid per anchor)
    for (int i = tid; i < N_TOT; i += NTHR) {
        const float* base; int H, W, n;
        if (i < 12288)      { base = p3; H = 64; W = 64; n = i; }
        else if (i < 15360) { base = p4; H = 32; W = 32; n = i - 12288; }
        else                { base = p5; H = 16; W = 16; n = i - 15360; }
        int a = n % 3; int hw = n / 3; int w = hw % W; int h = hw / W;
        const float* rec = base + (((b * H + h) * W + w) * 255 + a * 85);
        float s = sigf(rec[5 + c]) * sigf(rec[4]);
        skey[i] = __float_as_uint(s);   // s > 0 always -> positive-float bit order
    }
    if (tid == 0) sh_gcnt = 0;
    __syncthreads();

    radix_select_desc(skey, N_TOT, PRE_K, hist, sb0, sb1, &sh_thr, &sh_need);
    const u32 thr = sh_thr;
    const int need = sh_need;

    // ---- collect strictly-greater (unordered) + count ties per contiguous chunk
    int lc = 0;
    {
        const int base_i = tid * CHUNK2;
        for (int i = base_i; i < base_i + CHUNK2; ++i) {
            u32 k = skey[i];
            if (k > thr) {
                int p = atomicAdd(&sh_gcnt, 1);
                cand[p] = ((u64)k << 32) | (u32)(0xFFFFFFFFu - (u32)i);
            } else if (k == thr) ++lc;
        }
    }
    sb0[tid] = (u32)lc;
    __syncthreads();
    // exclusive prefix sum of tie counts (tie rank = index order, matches top_k tie-break)
    {
        u32* cur = sb0; u32* oth = sb1;
        for (int off = 1; off < 256; off <<= 1) {
            u32 v = cur[tid] + ((tid >= off) ? cur[tid - off] : 0u);
            oth[tid] = v;
            __syncthreads();
            u32* tmp = cur; cur = oth; oth = tmp;
        }
        const int excl0 = (int)cur[tid] - lc;
        const int G = sh_gcnt;            // atomics all done before scan barriers
        int r = excl0;
        const int base_i = tid * CHUNK2;
        for (int i = base_i; i < base_i + CHUNK2; ++i) {
            if (skey[i] == thr) {
                if (r < need) cand[G + r] = ((u64)thr << 32) | (u32)(0xFFFFFFFFu - (u32)i);
                ++r;
            }
        }
    }
    for (int t = PRE_K + tid; t < 512; t += NTHR) cand[t] = 0ull;
    __syncthreads();

    // ---- bitonic sort 512 desc (ties: larger ~idx first == smaller idx first)
    for (int k = 2; k <= 512; k <<= 1) {
        for (int j = k >> 1; j > 0; j >>= 1) {
            for (int i = tid; i < 512; i += NTHR) {
                int ixj = i ^ j;
                if (ixj > i) {
                    u64 va = cand[i], vb = cand[ixj];
                    bool desc = ((i & k) == 0);
                    if (desc ? (va < vb) : (va > vb)) { cand[i] = vb; cand[ixj] = va; }
                }
            }
            __syncthreads();
        }
    }

    // ---- overlay: sup matrix + box SoA onto dead skey region
    u64* sup  = (u64*)skey;              // [400*7] = 22400 B
    float* by1 = (float*)(skey + 5600);  // each 448 floats
    float* bx1 = by1 + 448;
    float* by2 = bx1 + 448;
    float* bx2 = by2 + 448;
    float* bar = bx2 + 448;

    for (int t = tid; t < PRE_K * 7; t += NTHR) sup[t] = 0ull;

    // ---- decode + clip top-400 boxes (SoA, padded to 448)
    for (int t = tid; t < 448; t += NTHR) {
        float y1 = 0.f, x1 = 0.f, y2 = 0.f, x2 = 0.f;
        if (t < PRE_K) {
            u64 key = cand[t];
            int idx = (int)(0xFFFFFFFFu - (u32)(key & 0xFFFFFFFFull));
            const float* base; const float* anc; int H, W, n; float sx, strd;
            if (idx < 12288)      { base = p3; anc = a3; H = 64; W = 64; n = idx;         sx = 1.2f;  strd = 8.f;  }
            else if (idx < 15360) { base = p4; anc = a4; H = 32; W = 32; n = idx - 12288; sx = 1.1f;  strd = 16.f; }
            else                  { base = p5; anc = a5; H = 16; W = 16; n = idx - 15360; sx = 1.05f; strd = 32.f; }
            int a = n % 3; int hw = n / 3; int w = hw % W; int h = hw / W;
            const float* rec = base + (((b * H + h) * W + w) * 255 + a * 85);
            float tx = rec[0], ty = rec[1], tw = rec[2], th = rec[3];
            float cx = (sigf(tx) * sx - 0.5f * (sx - 1.0f) + (float)w) / (float)W;
            float cy = (sigf(ty) * sx - 0.5f * (sx - 1.0f) + (float)h) / (float)H;
            float bw = expf(tw) * anc[a * 2 + 0] / ((float)W * strd);
            float bh = expf(th) * anc[a * 2 + 1] / ((float)H * strd);
            x1 = cx - 0.5f * bw; x2 = cx + 0.5f * bw;
            y1 = cy - 0.5f * bh; y2 = cy + 0.5f * bh;
            y1 = fminf(fmaxf(y1, 0.f), 1.f); x1 = fminf(fmaxf(x1, 0.f), 1.f);
            y2 = fminf(fmaxf(y2, 0.f), 1.f); x2 = fminf(fmaxf(x2, 0.f), 1.f);
        }
        by1[t] = y1; bx1[t] = x1; by2[t] = y2; bx2[t] = x2;
        bar[t] = (y2 - y1) * (x2 - x1);
    }
    __syncthreads();

    // ---- build suppression bitmask rows via ballot (upper triangle only)
    {
        const int wave = tid >> 6, lane = tid & 63;
        for (int row = wave; row < PRE_K; row += 4) {
            float ry1 = by1[row], rx1 = bx1[row], ry2 = by2[row], rx2 = bx2[row], ra = bar[row];
            int c0 = (row + 1) >> 6;
            for (int cw = c0; cw < 7; ++cw) {
                int j = (cw << 6) + lane;
                bool o = false;
                if (j > row && j < PRE_K) {
                    float ty = fmaxf(ry1, by1[j]);
                    float tx = fmaxf(rx1, bx1[j]);
                    float by = fminf(ry2, by2[j]);
                    float rx = fminf(rx2, bx2[j]);
                    float hh = fmaxf(by - ty, 0.f);
                    float ww = fmaxf(rx - tx, 0.f);
                    float inter = hh * ww;
                    float uni = ra + bar[j] - inter;
                    o = (inter / fmaxf(uni, 1e-9f)) > NMS_T;
                }
                u64 m = __ballot(o);
                if (lane == 0) sup[row * 7 + cw] = m;
            }
        }
    }
    __syncthreads();

    // ---- greedy suppression: single wave, keep bits in registers, no barriers
    if (tid < 64) {
        const int lane = tid;
        u64 kw = (lane < 6) ? ~0ull : ((lane == 6) ? 0xFFFFull : 0ull);
        for (int i = 0; i < PRE_K; ++i) {
            u64 kwv = __shfl(kw, i >> 6);
            if ((kwv >> (i & 63)) & 1ull) {            // wave-uniform branch
                u64 s = (lane < 7) ? sup[i * 7 + lane] : 0ull;
                kw &= ~s;
            }
        }
        if (lane < 7) keepw[lane] = kw;
    }
    __syncthreads();

    if (tid == 0) {
        int acc = 0;
        for (int w = 0; w < 7; ++w) { wpre[w] = acc; acc += (int)__popcll(keepw[w]); }
        sh_ncnt = acc < KEEP_CAP ? acc : KEEP_CAP;
    }
    __syncthreads();

    // ---- compact kept (rank via popcount), cap 200, zero-pad
    const int blk_out = b * NCLS + c;
    float* osc = ksc + (long)blk_out * KEEP_CAP;
    float* obx = kbox + (long)blk_out * KEEP_CAP * 4;
    for (int t = tid; t < PRE_K; t += NTHR) {
        int w = t >> 6, bb = t & 63;
        u64 kwv = keepw[w];
        if ((kwv >> bb) & 1ull) {
            int pos = wpre[w] + (int)__popcll(kwv & ((1ull << bb) - 1ull));
            if (pos < KEEP_CAP) {
                osc[pos] = __uint_as_float((u32)(cand[t] >> 32));
                obx[pos * 4 + 0] = by1[t]; obx[pos * 4 + 1] = bx1[t];
                obx[pos * 4 + 2] = by2[t]; obx[pos * 4 + 3] = bx2[t];
            }
        }
    }
    for (int t = sh_ncnt + tid; t < KEEP_CAP; t += NTHR) {
        osc[t] = 0.0f;
        obx[t * 4 + 0] = 0.f; obx[t * 4 + 1] = 0.f;
        obx[t * 4 + 2] = 0.f; obx[t * 4 + 3] = 0.f;
    }
}

// ---- Kernel B: per image: radix top-200 over 16000 compacted candidates -> outputs
__global__ __launch_bounds__(NTHR) void final_topk_kernel(
    const float* __restrict__ ksc, const float* __restrict__ kbox,
    float* __restrict__ out)
{
    __shared__ alignas(16) u32 skey[M_FIN];   // 64000 B
    __shared__ u64 cand[256];
    __shared__ u32 hist[256], sb0[256], sb1[256];
    __shared__ u32 sh_thr; __shared__ int sh_need, sh_gcnt;

    const int tid = threadIdx.x;
    const int b = blockIdx.x;
    const float* s_in = ksc + (long)b * M_FIN;

    for (int i = tid; i < M_FIN; i += NTHR) {
        float s = s_in[i];
        skey[i] = __float_as_uint(fmaxf(s, 0.0f));   // zeros stay key 0
    }
    if (tid == 0) sh_gcnt = 0;
    __syncthreads();

    radix_select_desc(skey, M_FIN, MAX_BOXES, hist, sb0, sb1, &sh_thr, &sh_need);
    const u32 thr = sh_thr;
    const int need = sh_need;

    int lc = 0;
    {
        const int base_i = tid * CHUNK3;
        const int lim_i = (base_i + CHUNK3 < M_FIN) ? (base_i + CHUNK3) : M_FIN;
        for (int i = base_i; i < lim_i; ++i) {
            u32 k = skey[i];
            if (k > thr) {
                int p = atomicAdd(&sh_gcnt, 1);
                cand[p] = ((u64)k << 32) | (u32)(0xFFFFFFFFu - (u32)i);
            } else if (k == thr) ++lc;
        }
    }
    sb0[tid] = (u32)lc;
    __syncthreads();
    {
        u32* cur = sb0; u32* oth = sb1;
        for (int off = 1; off < 256; off <<= 1) {
            u32 v = cur[tid] + ((tid >= off) ? cur[tid - off] : 0u);
            oth[tid] = v;
            __syncthreads();
            u32* tmp = cur; cur = oth; oth = tmp;
        }
        const int excl0 = (int)cur[tid] - lc;
        const int G = sh_gcnt;
        int r = excl0;
        const int base_i = tid * CHUNK3;
        const int lim_i = (base_i + CHUNK3 < M_FIN) ? (base_i + CHUNK3) : M_FIN;
        for (int i = base_i; i < lim_i; ++i) {
            if (skey[i] == thr) {
                if (r < need) cand[G + r] = ((u64)thr << 32) | (u32)(0xFFFFFFFFu - (u32)i);
                ++r;
            }
        }
    }
    if (tid >= MAX_BOXES) cand[tid] = 0ull;   // pad 200..255 (tid covers 0..255)
    __syncthreads();

    // bitonic sort 256 desc, one element per thread
    for (int k = 2; k <= 256; k <<= 1) {
        for (int j = k >> 1; j > 0; j >>= 1) {
            int ixj = tid ^ j;
            if (ixj > tid) {
                u64 va = cand[tid], vb = cand[ixj];
                bool desc = ((tid & k) == 0);
                if (desc ? (va < vb) : (va > vb)) { cand[tid] = vb; cand[ixj] = va; }
            }
            __syncthreads();
        }
    }

    float* obb = out;                         // (8,200,4)
    float* ocf = out + 8 * MAX_BOXES * 4;     // (8,200)
    float* ocl = ocf + 8 * MAX_BOXES;         // (8,200)
    float* onm = ocl + 8 * MAX_BOXES;         // (8,)

    float s = 0.f;
    if (tid < MAX_BOXES) {
        u64 key = cand[tid];
        s = __uint_as_float((u32)(key >> 32));
        float y1 = 0.f, x1 = 0.f, y2 = 0.f, x2 = 0.f, cid = 0.f;
        if (s > 0.0f) {
            int i = (int)(0xFFFFFFFFu - (u32)(key & 0xFFFFFFFFull));
            int cc = i / KEEP_CAP, j = i % KEEP_CAP;
            const float* bb = kbox + (((long)b * NCLS + cc) * KEEP_CAP + j) * 4;
            y1 = bb[0]; x1 = bb[1]; y2 = bb[2]; x2 = bb[3];
            cid = (float)cc;
        }
        long o = (long)b * MAX_BOXES + tid;
        obb[o * 4 + 0] = y1; obb[o * 4 + 1] = x1; obb[o * 4 + 2] = y2; obb[o * 4 + 3] = x2;
        ocf[o] = s; ocl[o] = cid;
    }
    int cnt = __syncthreads_count(tid < MAX_BOXES && s > 0.0f);
    if (tid == 0) onm[b] = (float)cnt;
}

extern "C" void kernel_launch(void* const* d_in, const int* in_sizes, int n_in,
                              void* d_out, int out_size, void* d_ws, size_t ws_size,
                              hipStream_t stream) {
    const float* p3 = (const float*)d_in[0];
    const float* p4 = (const float*)d_in[1];
    const float* p5 = (const float*)d_in[2];
    const float* a3 = (const float*)d_in[3];
    const float* a4 = (const float*)d_in[4];
    const float* a5 = (const float*)d_in[5];
    float* out = (float*)d_out;

    float* ksc  = (float*)d_ws;                 // 8*80*200 f32
    float* kbox = ksc + 8 * NCLS * KEEP_CAP;    // 8*80*200*4 f32

    topk_nms_kernel<<<8 * NCLS, NTHR, 0, stream>>>(p3, p4, p5, a3, a4, a5, ksc, kbox);
    final_topk_kernel<<<8, NTHR, 0, stream>>>(ksc, kbox, out);
}

// Round 3
// 312.825 us; speedup vs baseline: 12.4730x; 1.6089x over previous
//
#include <hip/hip_runtime.h>
#include <math.h>

#define NCLS 80
#define PRE_K 400
#define MAX_BOXES 200
#define KEEP_CAP 200
#define N_TOT 16128
#define M_FIN (NCLS * KEEP_CAP)   // 16000
#define NMS_T 0.6f
#define NTHR 512
#define CAP 512                    // candidate buffer size (>= K + tie margin)
#define HISTN (8 * 257)            // 8 per-wave histograms, 257-stride -> bank spread

typedef unsigned long long u64;
typedef unsigned int u32;

__device__ __forceinline__ float sigf(float x) { return 1.0f / (1.0f + expf(-x)); }

// aggregate per-wave hists, suffix-scan, pick digit d with S_d >= need > S_{d+1}
__device__ __forceinline__ void digit_select(u32* hist, u32* sb0, u32* sb1,
                                             u32* sh_dg, u32* sh_S1, u32* sh_T,
                                             int need, int tid)
{
    if (tid < 256) {
        u32 s = 0;
#pragma unroll
        for (int w = 0; w < 8; ++w) s += hist[w * 257 + tid];
        sb0[tid] = s;
    }
    __syncthreads();
    u32* cur = sb0; u32* oth = sb1;
    for (int off = 1; off < 256; off <<= 1) {
        if (tid < 256) oth[tid] = cur[tid] + ((tid + off < 256) ? cur[tid + off] : 0u);
        __syncthreads();
        u32* tmp = cur; cur = oth; oth = tmp;
    }
    if (tid < 256) {
        int Sd = (int)cur[tid];
        int Sd1 = (tid < 255) ? (int)cur[tid + 1] : 0;
        if (Sd >= need && need > Sd1) { *sh_dg = (u32)tid; *sh_S1 = (u32)Sd1; *sh_T = (u32)(Sd - Sd1); }
    }
    __syncthreads();
}

// Exact top-K select + full sort into cand[0..CAP). Pass-1 (shift 24) histogram
// must already be in hist. Result: cand sorted desc by (key32, ~idx); first K
// entries are exactly jax.lax.top_k's selection/order.
__device__ __forceinline__ void radix_topk_sort(
    const u32* __restrict__ skey, int n, int K,
    u64* cand, u32* hist, u32* sb0, u32* sb1,
    u32* sh_dg, u32* sh_S1, u32* sh_T, int* sh_gcnt, int tid)
{
    const int wv = tid >> 6;
    int need = K;

    digit_select(hist, sb0, sb1, sh_dg, sh_S1, sh_T, need, tid);
    u32 thr = *sh_dg; need -= (int)*sh_S1;
    int C = (K - need) + (int)*sh_T;
    int eshift = 24;

    for (int shift = 16; shift >= 0 && C > CAP; shift -= 8) {
        __syncthreads();
        for (int t = tid; t < HISTN; t += NTHR) hist[t] = 0u;
        __syncthreads();
        for (int i = tid; i < n; i += NTHR) {
            u32 k = skey[i];
            if ((k >> (shift + 8)) == thr)
                atomicAdd(&hist[wv * 257 + ((k >> shift) & 255u)], 1u);
        }
        __syncthreads();
        digit_select(hist, sb0, sb1, sh_dg, sh_S1, sh_T, need, tid);
        thr = (thr << 8) | *sh_dg; need -= (int)*sh_S1;
        C = (K - need) + (int)*sh_T;
        eshift = shift;
    }

    if (tid == 0) *sh_gcnt = 0;
    __syncthreads();

    if (C <= CAP) {
        // collect ALL keys with prefix >= thr; sort decides exact order/trim
        for (int i = tid; i < n; i += NTHR) {
            u32 k = skey[i];
            if ((k >> eshift) >= thr) {
                int p = atomicAdd(sh_gcnt, 1);
                cand[p] = ((u64)k << 32) | (u32)(0xFFFFFFFFu - (u32)i);
            }
        }
        __syncthreads();
        for (int t = C + tid; t < CAP; t += NTHR) cand[t] = 0ull;
    } else {
        // eshift==0, thr is the full 32-bit K-th key; idx-rank trim of exact ties
        for (int i = tid; i < n; i += NTHR) {
            u32 k = skey[i];
            if (k > thr) {
                int p = atomicAdd(sh_gcnt, 1);
                cand[p] = ((u64)k << 32) | (u32)(0xFFFFFFFFu - (u32)i);
            }
        }
        __syncthreads();
        const int G = *sh_gcnt;    // == K - need
        int lo = tid * 32; if (lo > n) lo = n;
        int hi = lo + 32;  if (hi > n) hi = n;
        int lc = 0;
        for (int i = lo; i < hi; ++i) if (skey[i] == thr) ++lc;
        u32* sc_cur = hist; u32* sc_oth = hist + 512;   // hist dead now
        sc_cur[tid] = (u32)lc;
        __syncthreads();
        for (int off = 1; off < NTHR; off <<= 1) {
            sc_oth[tid] = sc_cur[tid] + ((tid >= off) ? sc_cur[tid - off] : 0u);
            __syncthreads();
            u32* tmp = sc_cur; sc_cur = sc_oth; sc_oth = tmp;
        }
        int r = (int)sc_cur[tid] - lc;
        for (int i = lo; i < hi; ++i) {
            if (skey[i] == thr) {
                if (r < need) cand[G + r] = ((u64)thr << 32) | (u32)(0xFFFFFFFFu - (u32)i);
                ++r;
            }
        }
        __syncthreads();
        for (int t = K + tid; t < CAP; t += NTHR) cand[t] = 0ull;
    }
    __syncthreads();

    // bitonic sort CAP=512 desc, one element per thread
    for (int k2 = 2; k2 <= CAP; k2 <<= 1) {
        for (int j = k2 >> 1; j > 0; j >>= 1) {
            int ixj = tid ^ j;
            if (ixj > tid) {
                u64 va = cand[tid], vb = cand[ixj];
                bool desc = ((tid & k2) == 0);
                if (desc ? (va < vb) : (va > vb)) { cand[tid] = vb; cand[ixj] = va; }
            }
            __syncthreads();
        }
    }
}

// ---- Kernel A: per (image,class): adaptive radix top-400 -> sort -> bitmask NMS -> compact
__global__ __launch_bounds__(NTHR, 4) void topk_nms_kernel(
    const float* __restrict__ p3, const float* __restrict__ p4, const float* __restrict__ p5,
    const float* __restrict__ a3, const float* __restrict__ a4, const float* __restrict__ a5,
    float* __restrict__ ksc, float* __restrict__ kbox)
{
    __shared__ alignas(16) u32 skey[N_TOT];     // 64512 B; overlaid by sup+boxes in NMS phase
    __shared__ alignas(16) u64 cand[CAP];       // 4096 B
    __shared__ u32 hist[HISTN];                 // 8224 B
    __shared__ u32 sb0[256], sb1[256];          // 2048 B
    __shared__ u32 sh_dg, sh_S1, sh_T;
    __shared__ int sh_gcnt;
    __shared__ u64 keepw[7];
    __shared__ int wpre[8];
    __shared__ int sh_ncnt;

    const int tid = threadIdx.x;
    const int wv = tid >> 6;
    const int b = blockIdx.x & 7;     // image -> all 80 class-blocks of an image on one XCD
    const int c = blockIdx.x >> 3;

    // ---- score fill + fused pass-1 histogram
    for (int t = tid; t < HISTN; t += NTHR) hist[t] = 0u;
    __syncthreads();
    for (int i = tid; i < N_TOT; i += NTHR) {
        const float* base; int H, W, n;
        if (i < 12288)      { base = p3; H = 64; W = 64; n = i; }
        else if (i < 15360) { base = p4; H = 32; W = 32; n = i - 12288; }
        else                { base = p5; H = 16; W = 16; n = i - 15360; }
        int a = n % 3; int hw = n / 3; int w = hw % W; int h = hw / W;
        const float* rec = base + (((b * H + h) * W + w) * 255 + a * 85);
        float s = sigf(rec[5 + c]) * sigf(rec[4]);
        u32 k = __float_as_uint(s);       // s > 0 -> positive-float bit order
        skey[i] = k;
        atomicAdd(&hist[wv * 257 + (k >> 24)], 1u);
    }
    __syncthreads();

    radix_topk_sort(skey, N_TOT, PRE_K, cand, hist, sb0, sb1,
                    &sh_dg, &sh_S1, &sh_T, &sh_gcnt, tid);

    // ---- overlay: sup matrix + box SoA onto dead skey region
    u64* sup  = (u64*)skey;              // [400*7] u64 = 22400 B
    float* by1 = (float*)(skey + 5600);  // 448 floats each
    float* bx1 = by1 + 448;
    float* by2 = bx1 + 448;
    float* bx2 = by2 + 448;
    float* bar = bx2 + 448;

    for (int t = tid; t < PRE_K * 7; t += NTHR) sup[t] = 0ull;

    // ---- decode + clip top-400 boxes (SoA, padded to 448)
    for (int t = tid; t < 448; t += NTHR) {
        float y1 = 0.f, x1 = 0.f, y2 = 0.f, x2 = 0.f;
        if (t < PRE_K) {
            u64 key = cand[t];
            int idx = (int)(0xFFFFFFFFu - (u32)(key & 0xFFFFFFFFull));
            const float* base; const float* anc; int H, W, n; float sx, strd;
            if (idx < 12288)      { base = p3; anc = a3; H = 64; W = 64; n = idx;         sx = 1.2f;  strd = 8.f;  }
            else if (idx < 15360) { base = p4; anc = a4; H = 32; W = 32; n = idx - 12288; sx = 1.1f;  strd = 16.f; }
            else                  { base = p5; anc = a5; H = 16; W = 16; n = idx - 15360; sx = 1.05f; strd = 32.f; }
            int a = n % 3; int hw = n / 3; int w = hw % W; int h = hw / W;
            const float* rec = base + (((b * H + h) * W + w) * 255 + a * 85);
            float tx = rec[0], ty = rec[1], tw = rec[2], th = rec[3];
            float cx = (sigf(tx) * sx - 0.5f * (sx - 1.0f) + (float)w) / (float)W;
            float cy = (sigf(ty) * sx - 0.5f * (sx - 1.0f) + (float)h) / (float)H;
            float bw = expf(tw) * anc[a * 2 + 0] / ((float)W * strd);
            float bh = expf(th) * anc[a * 2 + 1] / ((float)H * strd);
            x1 = cx - 0.5f * bw; x2 = cx + 0.5f * bw;
            y1 = cy - 0.5f * bh; y2 = cy + 0.5f * bh;
            y1 = fminf(fmaxf(y1, 0.f), 1.f); x1 = fminf(fmaxf(x1, 0.f), 1.f);
            y2 = fminf(fmaxf(y2, 0.f), 1.f); x2 = fminf(fmaxf(x2, 0.f), 1.f);
        }
        by1[t] = y1; bx1[t] = x1; by2[t] = y2; bx2[t] = x2;
        bar[t] = (y2 - y1) * (x2 - x1);
    }
    __syncthreads();

    // ---- suppression bitmask rows via ballot (upper triangle), 8 waves
    {
        const int lane = tid & 63;
        for (int row = wv; row < PRE_K; row += 8) {
            float ry1 = by1[row], rx1 = bx1[row], ry2 = by2[row], rx2 = bx2[row], ra = bar[row];
            int c0 = (row + 1) >> 6;
            for (int cw = c0; cw < 7; ++cw) {
                int j = (cw << 6) + lane;
                bool o = false;
                if (j > row && j < PRE_K) {
                    float ty = fmaxf(ry1, by1[j]);
                    float tx = fmaxf(rx1, bx1[j]);
                    float by = fminf(ry2, by2[j]);
                    float rx = fminf(rx2, bx2[j]);
                    float hh = fmaxf(by - ty, 0.f);
                    float ww = fmaxf(rx - tx, 0.f);
                    float inter = hh * ww;
                    float uni = ra + bar[j] - inter;
                    o = (inter / fmaxf(uni, 1e-9f)) > NMS_T;
                }
                u64 m = __ballot(o);
                if (lane == 0) sup[row * 7 + cw] = m;
            }
        }
    }
    __syncthreads();

    // ---- greedy suppression: single wave, keep bits in registers, prefetched rows
    if (tid < 64) {
        u64 kw = (tid < 6) ? ~0ull : ((tid == 6) ? 0xFFFFull : 0ull);
        u64 s_cur = (tid < 7) ? sup[tid] : 0ull;   // row 0
        for (int i = 0; i < PRE_K; ++i) {
            u64 s_next = (tid < 7 && (i + 1) < PRE_K) ? sup[(i + 1) * 7 + tid] : 0ull;
            u64 kwv = __shfl(kw, i >> 6);
            if ((kwv >> (i & 63)) & 1ull) kw &= ~s_cur;   // wave-uniform branch
            s_cur = s_next;
        }
        if (tid < 7) keepw[tid] = kw;
    }
    __syncthreads();

    if (tid == 0) {
        int acc = 0;
        for (int w = 0; w < 7; ++w) { wpre[w] = acc; acc += (int)__popcll(keepw[w]); }
        sh_ncnt = acc < KEEP_CAP ? acc : KEEP_CAP;
    }
    __syncthreads();

    // ---- compact kept (rank via popcount), cap 200, zero-pad
    const int blk_out = b * NCLS + c;
    float* osc = ksc + (long)blk_out * KEEP_CAP;
    float* obx = kbox + (long)blk_out * KEEP_CAP * 4;
    for (int t = tid; t < PRE_K; t += NTHR) {
        int w = t >> 6, bb = t & 63;
        u64 kwv = keepw[w];
        if ((kwv >> bb) & 1ull) {
            int pos = wpre[w] + (int)__popcll(kwv & ((1ull << bb) - 1ull));
            if (pos < KEEP_CAP) {
                osc[pos] = __uint_as_float((u32)(cand[t] >> 32));
                obx[pos * 4 + 0] = by1[t]; obx[pos * 4 + 1] = bx1[t];
                obx[pos * 4 + 2] = by2[t]; obx[pos * 4 + 3] = bx2[t];
            }
        }
    }
    for (int t = sh_ncnt + tid; t < KEEP_CAP; t += NTHR) {
        osc[t] = 0.0f;
        obx[t * 4 + 0] = 0.f; obx[t * 4 + 1] = 0.f;
        obx[t * 4 + 2] = 0.f; obx[t * 4 + 3] = 0.f;
    }
}

// ---- Kernel B: per image: adaptive radix top-200 over 16000 candidates -> outputs
__global__ __launch_bounds__(NTHR, 4) void final_topk_kernel(
    const float* __restrict__ ksc, const float* __restrict__ kbox,
    float* __restrict__ out)
{
    __shared__ alignas(16) u32 skey[M_FIN];     // 64000 B
    __shared__ alignas(16) u64 cand[CAP];
    __shared__ u32 hist[HISTN];
    __shared__ u32 sb0[256], sb1[256];
    __shared__ u32 sh_dg, sh_S1, sh_T;
    __shared__ int sh_gcnt;

    const int tid = threadIdx.x;
    const int wv = tid >> 6;
    const int b = blockIdx.x;
    const float* s_in = ksc + (long)b * M_FIN;

    for (int t = tid; t < HISTN; t += NTHR) hist[t] = 0u;
    __syncthreads();
    for (int i = tid; i < M_FIN; i += NTHR) {
        u32 k = __float_as_uint(fmaxf(s_in[i], 0.0f));
        skey[i] = k;
        atomicAdd(&hist[wv * 257 + (k >> 24)], 1u);
    }
    __syncthreads();

    radix_topk_sort(skey, M_FIN, MAX_BOXES, cand, hist, sb0, sb1,
                    &sh_dg, &sh_S1, &sh_T, &sh_gcnt, tid);

    float* obb = out;                         // (8,200,4)
    float* ocf = out + 8 * MAX_BOXES * 4;     // (8,200)
    float* ocl = ocf + 8 * MAX_BOXES;         // (8,200)
    float* onm = ocl + 8 * MAX_BOXES;         // (8,)

    float s = 0.f;
    if (tid < MAX_BOXES) {
        u64 key = cand[tid];
        s = __uint_as_float((u32)(key >> 32));
        float y1 = 0.f, x1 = 0.f, y2 = 0.f, x2 = 0.f, cid = 0.f;
        if (s > 0.0f) {
            int i = (int)(0xFFFFFFFFu - (u32)(key & 0xFFFFFFFFull));
            int cc = i / KEEP_CAP, j = i % KEEP_CAP;
            const float* bb = kbox + (((long)b * NCLS + cc) * KEEP_CAP + j) * 4;
            y1 = bb[0]; x1 = bb[1]; y2 = bb[2]; x2 = bb[3];
            cid = (float)cc;
        }
        long o = (long)b * MAX_BOXES + tid;
        obb[o * 4 + 0] = y1; obb[o * 4 + 1] = x1; obb[o * 4 + 2] = y2; obb[o * 4 + 3] = x2;
        ocf[o] = s; ocl[o] = cid;
    }
    int cnt = __syncthreads_count(tid < MAX_BOXES && s > 0.0f);
    if (tid == 0) onm[b] = (float)cnt;
}

extern "C" void kernel_launch(void* const* d_in, const int* in_sizes, int n_in,
                              void* d_out, int out_size, void* d_ws, size_t ws_size,
                              hipStream_t stream) {
    const float* p3 = (const float*)d_in[0];
    const float* p4 = (const float*)d_in[1];
    const float* p5 = (const float*)d_in[2];
    const float* a3 = (const float*)d_in[3];
    const float* a4 = (const float*)d_in[4];
    const float* a5 = (const float*)d_in[5];
    float* out = (float*)d_out;

    float* ksc  = (float*)d_ws;                 // 8*80*200 f32
    float* kbox = ksc + 8 * NCLS * KEEP_CAP;    // 8*80*200*4 f32

    topk_nms_kernel<<<8 * NCLS, NTHR, 0, stream>>>(p3, p4, p5, a3, a4, a5, ksc, kbox);
    final_topk_kernel<<<8, NTHR, 0, stream>>>(ksc, kbox, out);
}

// Round 4
// 235.286 us; speedup vs baseline: 16.5835x; 1.3295x over previous
//
#include <hip/hip_runtime.h>
#include <math.h>

#define NCLS 80
#define PRE_K 400
#define MAX_BOXES 200
#define KEEP_CAP 200
#define N_TOT 16128
#define M_FIN (NCLS * KEEP_CAP)   // 16000
#define NMS_T 0.6f
#define NTHR 512
#define CAP 512                    // candidate buffer size (>= K + tie margin)
#define HISTN (8 * 257)            // 8 per-wave histograms, 257-stride -> bank spread

typedef unsigned long long u64;
typedef unsigned int u32;

__device__ __forceinline__ float sigf(float x) { return 1.0f / (1.0f + expf(-x)); }

// aggregate per-wave hists, suffix-scan, pick digit d with S_d >= need > S_{d+1}
__device__ __forceinline__ void digit_select(u32* hist, u32* sb0, u32* sb1,
                                             u32* sh_dg, u32* sh_S1, u32* sh_T,
                                             int need, int tid)
{
    if (tid < 256) {
        u32 s = 0;
#pragma unroll
        for (int w = 0; w < 8; ++w) s += hist[w * 257 + tid];
        sb0[tid] = s;
    }
    __syncthreads();
    u32* cur = sb0; u32* oth = sb1;
    for (int off = 1; off < 256; off <<= 1) {
        if (tid < 256) oth[tid] = cur[tid] + ((tid + off < 256) ? cur[tid + off] : 0u);
        __syncthreads();
        u32* tmp = cur; cur = oth; oth = tmp;
    }
    if (tid < 256) {
        int Sd = (int)cur[tid];
        int Sd1 = (tid < 255) ? (int)cur[tid + 1] : 0;
        if (Sd >= need && need > Sd1) { *sh_dg = (u32)tid; *sh_S1 = (u32)Sd1; *sh_T = (u32)(Sd - Sd1); }
    }
    __syncthreads();
}

// Exact top-K select + full sort into cand[0..CAP). Pass-1 (shift 24) histogram
// must already be in hist. keys may point to LDS or global (positive-float bits).
// Result: cand sorted desc by (key32, ~idx); first K entries match jax.lax.top_k.
__device__ __forceinline__ void radix_topk_sort(
    const u32* __restrict__ keys, int n, int K,
    u64* cand, u32* hist, u32* sb0, u32* sb1,
    u32* sh_dg, u32* sh_S1, u32* sh_T, int* sh_gcnt, int tid)
{
    const int wv = tid >> 6;
    int need = K;

    digit_select(hist, sb0, sb1, sh_dg, sh_S1, sh_T, need, tid);
    u32 thr = *sh_dg; need -= (int)*sh_S1;
    int C = (K - need) + (int)*sh_T;
    int eshift = 24;

    for (int shift = 16; shift >= 0 && C > CAP; shift -= 8) {
        __syncthreads();
        for (int t = tid; t < HISTN; t += NTHR) hist[t] = 0u;
        __syncthreads();
        for (int i = tid; i < n; i += NTHR) {
            u32 k = keys[i];
            if ((k >> (shift + 8)) == thr)
                atomicAdd(&hist[wv * 257 + ((k >> shift) & 255u)], 1u);
        }
        __syncthreads();
        digit_select(hist, sb0, sb1, sh_dg, sh_S1, sh_T, need, tid);
        thr = (thr << 8) | *sh_dg; need -= (int)*sh_S1;
        C = (K - need) + (int)*sh_T;
        eshift = shift;
    }

    if (tid == 0) *sh_gcnt = 0;
    __syncthreads();

    if (C <= CAP) {
        // collect ALL keys with prefix >= thr; sort decides exact order/trim
        for (int i = tid; i < n; i += NTHR) {
            u32 k = keys[i];
            if ((k >> eshift) >= thr) {
                int p = atomicAdd(sh_gcnt, 1);
                cand[p] = ((u64)k << 32) | (u32)(0xFFFFFFFFu - (u32)i);
            }
        }
        __syncthreads();
        for (int t = C + tid; t < CAP; t += NTHR) cand[t] = 0ull;
    } else {
        // eshift==0, thr is the full 32-bit K-th key; idx-rank trim of exact ties
        for (int i = tid; i < n; i += NTHR) {
            u32 k = keys[i];
            if (k > thr) {
                int p = atomicAdd(sh_gcnt, 1);
                cand[p] = ((u64)k << 32) | (u32)(0xFFFFFFFFu - (u32)i);
            }
        }
        __syncthreads();
        const int G = *sh_gcnt;    // == K - need
        int lo = tid * 32; if (lo > n) lo = n;
        int hi = lo + 32;  if (hi > n) hi = n;
        int lc = 0;
        for (int i = lo; i < hi; ++i) if (keys[i] == thr) ++lc;
        u32* sc_cur = hist; u32* sc_oth = hist + 512;   // hist dead now
        sc_cur[tid] = (u32)lc;
        __syncthreads();
        for (int off = 1; off < NTHR; off <<= 1) {
            sc_oth[tid] = sc_cur[tid] + ((tid >= off) ? sc_cur[tid - off] : 0u);
            __syncthreads();
            u32* tmp = sc_cur; sc_cur = sc_oth; sc_oth = tmp;
        }
        int r = (int)sc_cur[tid] - lc;
        for (int i = lo; i < hi; ++i) {
            if (keys[i] == thr) {
                if (r < need) cand[G + r] = ((u64)thr << 32) | (u32)(0xFFFFFFFFu - (u32)i);
                ++r;
            }
        }
        __syncthreads();
        for (int t = K + tid; t < CAP; t += NTHR) cand[t] = 0ull;
    }
    __syncthreads();

    // ---- bitonic sort CAP=512 desc: k<=64 in-wave via shfl_xor, 6 LDS stages only
    u64 v = cand[tid];
#pragma unroll
    for (int k2 = 2; k2 <= 64; k2 <<= 1) {
#pragma unroll
        for (int j = k2 >> 1; j > 0; j >>= 1) {
            u64 p = __shfl_xor(v, j, 64);
            bool takeMax = ((tid & k2) == 0) ^ ((tid & j) != 0);
            v = takeMax ? (v >= p ? v : p) : (v <= p ? v : p);
        }
    }
    for (int k2 = 128; k2 <= CAP; k2 <<= 1) {
        for (int j = k2 >> 1; j >= 64; j >>= 1) {
            __syncthreads();
            cand[tid] = v;
            __syncthreads();
            u64 p = cand[tid ^ j];
            bool takeMax = ((tid & k2) == 0) ^ ((tid & j) != 0);
            v = takeMax ? (v >= p ? v : p) : (v <= p ? v : p);
        }
#pragma unroll
        for (int j = 32; j > 0; j >>= 1) {
            u64 p = __shfl_xor(v, j, 64);
            bool takeMax = ((tid & k2) == 0) ^ ((tid & j) != 0);
            v = takeMax ? (v >= p ? v : p) : (v <= p ? v : p);
        }
    }
    __syncthreads();
    cand[tid] = v;
    __syncthreads();
}

// ---- Stage 1: decode all scores [b][c][n] and clipped boxes float4[b][n] once
__global__ __launch_bounds__(256) void decode_kernel(
    const float* __restrict__ p3, const float* __restrict__ p4, const float* __restrict__ p5,
    const float* __restrict__ a3, const float* __restrict__ a4, const float* __restrict__ a5,
    float* __restrict__ scores, float* __restrict__ boxes)
{
    const int blk = blockIdx.x;
    const int b = blk & 7;
    const int n = ((blk >> 3) << 8) + threadIdx.x;

    const float* base; const float* anc; int logw, nn; float sx;
    if (n < 12288)      { base = p3; anc = a3; logw = 6; nn = n;         sx = 1.2f;  }
    else if (n < 15360) { base = p4; anc = a4; logw = 5; nn = n - 12288; sx = 1.1f;  }
    else                { base = p5; anc = a5; logw = 4; nn = n - 15360; sx = 1.05f; }
    const int W = 1 << logw;
    const int a = nn % 3; const int hw = nn / 3;
    const int w = hw & (W - 1); const int h = hw >> logw;
    const float winv = 1.0f / (float)W;
    const float* rec = base + ((size_t)((b * W + h) * W + w) * 255 + a * 85);

    float tx = rec[0], ty = rec[1], tw = rec[2], th = rec[3], to = rec[4];
    float sobj = sigf(to);
    float cx = (sigf(tx) * sx - 0.5f * (sx - 1.0f) + (float)w) * winv;
    float cy = (sigf(ty) * sx - 0.5f * (sx - 1.0f) + (float)h) * winv;
    float bw = expf(tw) * anc[a * 2 + 0] * (1.0f / 512.0f);   // W*stride == 512 all levels
    float bh = expf(th) * anc[a * 2 + 1] * (1.0f / 512.0f);
    float x1 = cx - 0.5f * bw, x2 = cx + 0.5f * bw;
    float y1 = cy - 0.5f * bh, y2 = cy + 0.5f * bh;
    y1 = fminf(fmaxf(y1, 0.f), 1.f); x1 = fminf(fmaxf(x1, 0.f), 1.f);
    y2 = fminf(fmaxf(y2, 0.f), 1.f); x2 = fminf(fmaxf(x2, 0.f), 1.f);
    float4 bb; bb.x = y1; bb.y = x1; bb.z = y2; bb.w = x2;
    ((float4*)boxes)[b * N_TOT + n] = bb;

    float* sb = scores + (long)b * NCLS * N_TOT + n;
#pragma unroll 8
    for (int cc = 0; cc < NCLS; ++cc)
        sb[(long)cc * N_TOT] = sigf(rec[5 + cc]) * sobj;
}

// ---- Stage 2 (fused path): per (image,class) top-400 -> NMS -> compact
__global__ __launch_bounds__(NTHR, 6) void topk_nms_fused(
    const float* __restrict__ scores, const float* __restrict__ boxes,
    float* __restrict__ ksc, float* __restrict__ kbox)
{
    __shared__ alignas(16) u64 cand[CAP];
    __shared__ u32 hist[HISTN];
    __shared__ u32 sb0[256], sb1[256];
    __shared__ u32 sh_dg, sh_S1, sh_T;
    __shared__ int sh_gcnt;
    __shared__ u64 sup[PRE_K * 7];                       // 22400 B
    __shared__ float by1[448], bx1[448], by2[448], bx2[448], bar[448];
    __shared__ u64 keepw[7];
    __shared__ int wpre[8];
    __shared__ int sh_ncnt;

    const int tid = threadIdx.x;
    const int wv = tid >> 6;
    const int b = blockIdx.x & 7;     // all 80 class-blocks of an image on one XCD
    const int c = blockIdx.x >> 3;

    const u32* keys = (const u32*)(scores + (long)(b * NCLS + c) * N_TOT);

    // pass-1 histogram, vectorized coalesced read
    for (int t = tid; t < HISTN; t += NTHR) hist[t] = 0u;
    __syncthreads();
    const uint4* k4 = (const uint4*)keys;
#pragma unroll
    for (int it = 0; it < 8; ++it) {
        int i4 = tid + it * NTHR;
        if (i4 < N_TOT / 4) {
            uint4 kk = k4[i4];
            atomicAdd(&hist[wv * 257 + (kk.x >> 24)], 1u);
            atomicAdd(&hist[wv * 257 + (kk.y >> 24)], 1u);
            atomicAdd(&hist[wv * 257 + (kk.z >> 24)], 1u);
            atomicAdd(&hist[wv * 257 + (kk.w >> 24)], 1u);
        }
    }
    __syncthreads();

    radix_topk_sort(keys, N_TOT, PRE_K, cand, hist, sb0, sb1,
                    &sh_dg, &sh_S1, &sh_T, &sh_gcnt, tid);

    for (int t = tid; t < PRE_K * 7; t += NTHR) sup[t] = 0ull;

    // gather top-400 boxes from table (SoA, padded to 448)
    const float4* btab = (const float4*)boxes;
    for (int t = tid; t < 448; t += NTHR) {
        float y1 = 0.f, x1 = 0.f, y2 = 0.f, x2 = 0.f;
        if (t < PRE_K) {
            u64 key = cand[t];
            if ((key >> 32) != 0ull) {
                int idx = (int)(0xFFFFFFFFu - (u32)(key & 0xFFFFFFFFull));
                float4 bb = btab[b * N_TOT + idx];
                y1 = bb.x; x1 = bb.y; y2 = bb.z; x2 = bb.w;
            }
        }
        by1[t] = y1; bx1[t] = x1; by2[t] = y2; bx2[t] = x2;
        bar[t] = (y2 - y1) * (x2 - x1);
    }
    __syncthreads();

    // suppression bitmask rows via ballot (upper triangle), 8 waves
    {
        const int lane = tid & 63;
        for (int row = wv; row < PRE_K; row += 8) {
            float ry1 = by1[row], rx1 = bx1[row], ry2 = by2[row], rx2 = bx2[row], ra = bar[row];
            int c0 = (row + 1) >> 6;
            for (int cw = c0; cw < 7; ++cw) {
                int j = (cw << 6) + lane;
                bool o = false;
                if (j > row && j < PRE_K) {
                    float ty = fmaxf(ry1, by1[j]);
                    float tx = fmaxf(rx1, bx1[j]);
                    float by = fminf(ry2, by2[j]);
                    float rx = fminf(rx2, bx2[j]);
                    float hh = fmaxf(by - ty, 0.f);
                    float ww = fmaxf(rx - tx, 0.f);
                    float inter = hh * ww;
                    float uni = ra + bar[j] - inter;
                    o = (inter / fmaxf(uni, 1e-9f)) > NMS_T;
                }
                u64 m = __ballot(o);
                if (lane == 0) sup[row * 7 + cw] = m;
            }
        }
    }
    __syncthreads();

    // greedy suppression: single wave, keep bits in registers, prefetched rows
    if (tid < 64) {
        u64 kw = (tid < 6) ? ~0ull : ((tid == 6) ? 0xFFFFull : 0ull);
        u64 s_cur = (tid < 7) ? sup[tid] : 0ull;
        for (int i = 0; i < PRE_K; ++i) {
            u64 s_next = (tid < 7 && (i + 1) < PRE_K) ? sup[(i + 1) * 7 + tid] : 0ull;
            u64 kwv = __shfl(kw, i >> 6);
            if ((kwv >> (i & 63)) & 1ull) kw &= ~s_cur;
            s_cur = s_next;
        }
        if (tid < 7) keepw[tid] = kw;
    }
    __syncthreads();

    if (tid == 0) {
        int acc = 0;
        for (int w = 0; w < 7; ++w) { wpre[w] = acc; acc += (int)__popcll(keepw[w]); }
        sh_ncnt = acc < KEEP_CAP ? acc : KEEP_CAP;
    }
    __syncthreads();

    const int blk_out = b * NCLS + c;
    float* osc = ksc + (long)blk_out * KEEP_CAP;
    float* obx = kbox + (long)blk_out * KEEP_CAP * 4;
    for (int t = tid; t < PRE_K; t += NTHR) {
        int w = t >> 6, bb = t & 63;
        u64 kwv = keepw[w];
        if ((kwv >> bb) & 1ull) {
            int pos = wpre[w] + (int)__popcll(kwv & ((1ull << bb) - 1ull));
            if (pos < KEEP_CAP) {
                osc[pos] = __uint_as_float((u32)(cand[t] >> 32));
                obx[pos * 4 + 0] = by1[t]; obx[pos * 4 + 1] = bx1[t];
                obx[pos * 4 + 2] = by2[t]; obx[pos * 4 + 3] = bx2[t];
            }
        }
    }
    for (int t = sh_ncnt + tid; t < KEEP_CAP; t += NTHR) {
        osc[t] = 0.0f;
        obx[t * 4 + 0] = 0.f; obx[t * 4 + 1] = 0.f;
        obx[t * 4 + 2] = 0.f; obx[t * 4 + 3] = 0.f;
    }
}

// ---- Fallback monolithic stage-2 (R3-proven) if ws too small for score table
__global__ __launch_bounds__(NTHR, 4) void topk_nms_mono(
    const float* __restrict__ p3, const float* __restrict__ p4, const float* __restrict__ p5,
    const float* __restrict__ a3, const float* __restrict__ a4, const float* __restrict__ a5,
    float* __restrict__ ksc, float* __restrict__ kbox)
{
    __shared__ alignas(16) u32 skey[N_TOT];
    __shared__ alignas(16) u64 cand[CAP];
    __shared__ u32 hist[HISTN];
    __shared__ u32 sb0[256], sb1[256];
    __shared__ u32 sh_dg, sh_S1, sh_T;
    __shared__ int sh_gcnt;
    __shared__ u64 keepw[7];
    __shared__ int wpre[8];
    __shared__ int sh_ncnt;

    const int tid = threadIdx.x;
    const int wv = tid >> 6;
    const int b = blockIdx.x & 7;
    const int c = blockIdx.x >> 3;

    for (int t = tid; t < HISTN; t += NTHR) hist[t] = 0u;
    __syncthreads();
    for (int i = tid; i < N_TOT; i += NTHR) {
        const float* base; int H, W, n;
        if (i < 12288)      { base = p3; H = 64; W = 64; n = i; }
        else if (i < 15360) { base = p4; H = 32; W = 32; n = i - 12288; }
        else                { base = p5; H = 16; W = 16; n = i - 15360; }
        int a = n % 3; int hw = n / 3; int w = hw % W; int h = hw / W;
        const float* rec = base + (((b * H + h) * W + w) * 255 + a * 85);
        float s = sigf(rec[5 + c]) * sigf(rec[4]);
        u32 k = __float_as_uint(s);
        skey[i] = k;
        atomicAdd(&hist[wv * 257 + (k >> 24)], 1u);
    }
    __syncthreads();

    radix_topk_sort(skey, N_TOT, PRE_K, cand, hist, sb0, sb1,
                    &sh_dg, &sh_S1, &sh_T, &sh_gcnt, tid);

    u64* sup  = (u64*)skey;
    float* by1 = (float*)(skey + 5600);
    float* bx1 = by1 + 448;
    float* by2 = bx1 + 448;
    float* bx2 = by2 + 448;
    float* bar = bx2 + 448;

    for (int t = tid; t < PRE_K * 7; t += NTHR) sup[t] = 0ull;

    for (int t = tid; t < 448; t += NTHR) {
        float y1 = 0.f, x1 = 0.f, y2 = 0.f, x2 = 0.f;
        if (t < PRE_K) {
            u64 key = cand[t];
            if ((key >> 32) != 0ull) {
                int idx = (int)(0xFFFFFFFFu - (u32)(key & 0xFFFFFFFFull));
                const float* base; const float* anc; int H, W, n; float sx, strd;
                if (idx < 12288)      { base = p3; anc = a3; H = 64; W = 64; n = idx;         sx = 1.2f;  strd = 8.f;  }
                else if (idx < 15360) { base = p4; anc = a4; H = 32; W = 32; n = idx - 12288; sx = 1.1f;  strd = 16.f; }
                else                  { base = p5; anc = a5; H = 16; W = 16; n = idx - 15360; sx = 1.05f; strd = 32.f; }
                int a = n % 3; int hw = n / 3; int w = hw % W; int h = hw / W;
                const float* rec = base + (((b * H + h) * W + w) * 255 + a * 85);
                float tx = rec[0], ty = rec[1], tw = rec[2], th = rec[3];
                float cx = (sigf(tx) * sx - 0.5f * (sx - 1.0f) + (float)w) / (float)W;
                float cy = (sigf(ty) * sx - 0.5f * (sx - 1.0f) + (float)h) / (float)H;
                float bw = expf(tw) * anc[a * 2 + 0] / ((float)W * strd);
                float bh = expf(th) * anc[a * 2 + 1] / ((float)H * strd);
                x1 = cx - 0.5f * bw; x2 = cx + 0.5f * bw;
                y1 = cy - 0.5f * bh; y2 = cy + 0.5f * bh;
                y1 = fminf(fmaxf(y1, 0.f), 1.f); x1 = fminf(fmaxf(x1, 0.f), 1.f);
                y2 = fminf(fmaxf(y2, 0.f), 1.f); x2 = fminf(fmaxf(x2, 0.f), 1.f);
            }
        }
        by1[t] = y1; bx1[t] = x1; by2[t] = y2; bx2[t] = x2;
        bar[t] = (y2 - y1) * (x2 - x1);
    }
    __syncthreads();

    {
        const int lane = tid & 63;
        for (int row = wv; row < PRE_K; row += 8) {
            float ry1 = by1[row], rx1 = bx1[row], ry2 = by2[row], rx2 = bx2[row], ra = bar[row];
            int c0 = (row + 1) >> 6;
            for (int cw = c0; cw < 7; ++cw) {
                int j = (cw << 6) + lane;
                bool o = false;
                if (j > row && j < PRE_K) {
                    float ty = fmaxf(ry1, by1[j]);
                    float tx = fmaxf(rx1, bx1[j]);
                    float by = fminf(ry2, by2[j]);
                    float rx = fminf(rx2, bx2[j]);
                    float hh = fmaxf(by - ty, 0.f);
                    float ww = fmaxf(rx - tx, 0.f);
                    float inter = hh * ww;
                    float uni = ra + bar[j] - inter;
                    o = (inter / fmaxf(uni, 1e-9f)) > NMS_T;
                }
                u64 m = __ballot(o);
                if (lane == 0) sup[row * 7 + cw] = m;
            }
        }
    }
    __syncthreads();

    if (tid < 64) {
        u64 kw = (tid < 6) ? ~0ull : ((tid == 6) ? 0xFFFFull : 0ull);
        u64 s_cur = (tid < 7) ? sup[tid] : 0ull;
        for (int i = 0; i < PRE_K; ++i) {
            u64 s_next = (tid < 7 && (i + 1) < PRE_K) ? sup[(i + 1) * 7 + tid] : 0ull;
            u64 kwv = __shfl(kw, i >> 6);
            if ((kwv >> (i & 63)) & 1ull) kw &= ~s_cur;
            s_cur = s_next;
        }
        if (tid < 7) keepw[tid] = kw;
    }
    __syncthreads();

    if (tid == 0) {
        int acc = 0;
        for (int w = 0; w < 7; ++w) { wpre[w] = acc; acc += (int)__popcll(keepw[w]); }
        sh_ncnt = acc < KEEP_CAP ? acc : KEEP_CAP;
    }
    __syncthreads();

    const int blk_out = b * NCLS + c;
    float* osc = ksc + (long)blk_out * KEEP_CAP;
    float* obx = kbox + (long)blk_out * KEEP_CAP * 4;
    for (int t = tid; t < PRE_K; t += NTHR) {
        int w = t >> 6, bb = t & 63;
        u64 kwv = keepw[w];
        if ((kwv >> bb) & 1ull) {
            int pos = wpre[w] + (int)__popcll(kwv & ((1ull << bb) - 1ull));
            if (pos < KEEP_CAP) {
                osc[pos] = __uint_as_float((u32)(cand[t] >> 32));
                obx[pos * 4 + 0] = by1[t]; obx[pos * 4 + 1] = bx1[t];
                obx[pos * 4 + 2] = by2[t]; obx[pos * 4 + 3] = bx2[t];
            }
        }
    }
    for (int t = sh_ncnt + tid; t < KEEP_CAP; t += NTHR) {
        osc[t] = 0.0f;
        obx[t * 4 + 0] = 0.f; obx[t * 4 + 1] = 0.f;
        obx[t * 4 + 2] = 0.f; obx[t * 4 + 3] = 0.f;
    }
}

// ---- Stage 3: per image top-200 over 16000 compacted candidates -> outputs
__global__ __launch_bounds__(NTHR) void final_topk_kernel(
    const float* __restrict__ ksc, const float* __restrict__ kbox,
    float* __restrict__ out)
{
    __shared__ alignas(16) u64 cand[CAP];
    __shared__ u32 hist[HISTN];
    __shared__ u32 sb0[256], sb1[256];
    __shared__ u32 sh_dg, sh_S1, sh_T;
    __shared__ int sh_gcnt;

    const int tid = threadIdx.x;
    const int wv = tid >> 6;
    const int b = blockIdx.x;
    const u32* keys = (const u32*)(ksc + (long)b * M_FIN);

    for (int t = tid; t < HISTN; t += NTHR) hist[t] = 0u;
    __syncthreads();
    const uint4* k4 = (const uint4*)keys;
#pragma unroll
    for (int it = 0; it < 8; ++it) {
        int i4 = tid + it * NTHR;
        if (i4 < M_FIN / 4) {
            uint4 kk = k4[i4];
            atomicAdd(&hist[wv * 257 + (kk.x >> 24)], 1u);
            atomicAdd(&hist[wv * 257 + (kk.y >> 24)], 1u);
            atomicAdd(&hist[wv * 257 + (kk.z >> 24)], 1u);
            atomicAdd(&hist[wv * 257 + (kk.w >> 24)], 1u);
        }
    }
    __syncthreads();

    radix_topk_sort(keys, M_FIN, MAX_BOXES, cand, hist, sb0, sb1,
                    &sh_dg, &sh_S1, &sh_T, &sh_gcnt, tid);

    float* obb = out;                         // (8,200,4)
    float* ocf = out + 8 * MAX_BOXES * 4;     // (8,200)
    float* ocl = ocf + 8 * MAX_BOXES;         // (8,200)
    float* onm = ocl + 8 * MAX_BOXES;         // (8,)

    float s = 0.f;
    if (tid < MAX_BOXES) {
        u64 key = cand[tid];
        s = __uint_as_float((u32)(key >> 32));
        float y1 = 0.f, x1 = 0.f, y2 = 0.f, x2 = 0.f, cid = 0.f;
        if (s > 0.0f) {
            int i = (int)(0xFFFFFFFFu - (u32)(key & 0xFFFFFFFFull));
            int cc = i / KEEP_CAP, j = i % KEEP_CAP;
            const float* bb = kbox + (((long)b * NCLS + cc) * KEEP_CAP + j) * 4;
            y1 = bb[0]; x1 = bb[1]; y2 = bb[2]; x2 = bb[3];
            cid = (float)cc;
        }
        long o = (long)b * MAX_BOXES + tid;
        obb[o * 4 + 0] = y1; obb[o * 4 + 1] = x1; obb[o * 4 + 2] = y2; obb[o * 4 + 3] = x2;
        ocf[o] = s; ocl[o] = cid;
    }
    int cnt = __syncthreads_count(tid < MAX_BOXES && s > 0.0f);
    if (tid == 0) onm[b] = (float)cnt;
}

extern "C" void kernel_launch(void* const* d_in, const int* in_sizes, int n_in,
                              void* d_out, int out_size, void* d_ws, size_t ws_size,
                              hipStream_t stream) {
    const float* p3 = (const float*)d_in[0];
    const float* p4 = (const float*)d_in[1];
    const float* p5 = (const float*)d_in[2];
    const float* a3 = (const float*)d_in[3];
    const float* a4 = (const float*)d_in[4];
    const float* a5 = (const float*)d_in[5];
    float* out = (float*)d_out;

    const size_t score_bytes = (size_t)8 * NCLS * N_TOT * 4;      // 41,287,680
    const size_t boxes_bytes = (size_t)8 * N_TOT * 16;            //  2,064,384
    const size_t ksc_bytes   = (size_t)8 * NCLS * KEEP_CAP * 4;   //    512,000
    const size_t kbox_bytes  = (size_t)8 * NCLS * KEEP_CAP * 16;  //  2,048,000

    if (ws_size >= score_bytes + boxes_bytes + ksc_bytes + kbox_bytes) {
        float* scores = (float*)d_ws;
        float* boxes  = (float*)((char*)d_ws + score_bytes);
        float* ksc    = (float*)((char*)d_ws + score_bytes + boxes_bytes);
        float* kbox   = (float*)((char*)d_ws + score_bytes + boxes_bytes + ksc_bytes);
        decode_kernel<<<504, 256, 0, stream>>>(p3, p4, p5, a3, a4, a5, scores, boxes);
        topk_nms_fused<<<8 * NCLS, NTHR, 0, stream>>>(scores, boxes, ksc, kbox);
        final_topk_kernel<<<8, NTHR, 0, stream>>>(ksc, kbox, out);
    } else {
        float* ksc  = (float*)d_ws;
        float* kbox = ksc + 8 * NCLS * KEEP_CAP;
        topk_nms_mono<<<8 * NCLS, NTHR, 0, stream>>>(p3, p4, p5, a3, a4, a5, ksc, kbox);
        final_topk_kernel<<<8, NTHR, 0, stream>>>(ksc, kbox, out);
    }
}

// Round 5
// 195.600 us; speedup vs baseline: 19.9482x; 1.2029x over previous
//
#include <hip/hip_runtime.h>
#include <math.h>

#define NCLS 80
#define PRE_K 400
#define MAX_BOXES 200
#define KEEP_CAP 200
#define N_TOT 16128
#define M_FIN (NCLS * KEEP_CAP)   // 16000
#define NMS_T 0.6f
#define NTHR 512
#define CAP 512                    // candidate buffer (>= K + tie margin)

typedef unsigned long long u64;
typedef unsigned int u32;

__device__ __forceinline__ float sigf(float x) { return 1.0f / (1.0f + expf(-x)); }

// wave-aggregated LDS histogram add: one atomic per distinct digit per wave
__device__ __forceinline__ void hist_agg(u32* hist, u32 d, bool valid, int lane)
{
    u64 act = __ballot(valid);
    while (act) {
        int ldr = __ffsll((unsigned long long)act) - 1;
        u32 dl = __shfl(d, ldr, 64);
        u64 m = __ballot(valid && d == dl);
        if (lane == ldr) atomicAdd(&hist[dl], (u32)__popcll(m));
        act &= ~m;
    }
}

// hist[256] -> digit d with S_d >= need > S_{d+1}; wave 0 only, 1 barrier.
__device__ __forceinline__ void digit_select(const u32* hist, int need,
                                             u32* sh_dg, u32* sh_S1, u32* sh_T, int tid)
{
    if (tid < 64) {
        const int lane = tid;
        u32 h0 = hist[4 * lane + 0], h1 = hist[4 * lane + 1];
        u32 h2 = hist[4 * lane + 2], h3 = hist[4 * lane + 3];
        u32 loc = h0 + h1 + h2 + h3;
        u32 s = loc;
#pragma unroll
        for (int off = 1; off < 64; off <<= 1) {
            u32 t = __shfl_down(s, off, 64);
            if (lane + off < 64) s += t;
        }
        u32 after = s - loc;                      // sum over digits > 4*lane+3
        u32 S3 = h3 + after, S2 = h2 + S3, S1v = h1 + S2, S0 = h0 + S1v;
        u32 Sarr[5] = { S0, S1v, S2, S3, after };
#pragma unroll
        for (int k = 0; k < 4; ++k) {
            if ((int)Sarr[k] >= need && need > (int)Sarr[k + 1]) {
                *sh_dg = (u32)(4 * lane + k);
                *sh_S1 = Sarr[k + 1];
                *sh_T  = Sarr[k] - Sarr[k + 1];
            }
        }
    }
    __syncthreads();
}

// Exact top-K select + full sort into cand[0..CAP). Pass-1 (shift 24) histogram
// must already be in hist; sh_gcnt must be zeroed by caller before the last
// barrier. keys: u32 positive-float bits (LDS or global, 16B-aligned, n%4==0).
// scr: >= 1024 u32 scratch (used only on the rare full-32-bit-tie path).
// Result: cand sorted desc by (key32, ~idx); first K entries match jax.lax.top_k.
__device__ __forceinline__ void radix_topk_sort(
    const u32* __restrict__ keys, int n, int K,
    u64* cand, u32* hist, u32* scr,
    u32* sh_dg, u32* sh_S1, u32* sh_T, int* sh_gcnt, int tid)
{
    int need = K;
    digit_select(hist, need, sh_dg, sh_S1, sh_T, tid);
    u32 thr = *sh_dg; need -= (int)*sh_S1;
    int C = (K - need) + (int)*sh_T;
    int eshift = 24;

    const uint4* k4 = (const uint4*)keys;
    const int n4 = n >> 2;
    const int nIter = (n4 + NTHR - 1) / NTHR;

    for (int shift = 16; shift >= 0 && C > CAP; shift -= 8) {
        if (tid < 256) hist[tid] = 0u;
        __syncthreads();
        for (int it = 0; it < nIter; ++it) {
            int i4 = tid + it * NTHR;
            if (i4 < n4) {
                uint4 kk = k4[i4];
                if ((kk.x >> (shift + 8)) == thr) atomicAdd(&hist[(kk.x >> shift) & 255u], 1u);
                if ((kk.y >> (shift + 8)) == thr) atomicAdd(&hist[(kk.y >> shift) & 255u], 1u);
                if ((kk.z >> (shift + 8)) == thr) atomicAdd(&hist[(kk.z >> shift) & 255u], 1u);
                if ((kk.w >> (shift + 8)) == thr) atomicAdd(&hist[(kk.w >> shift) & 255u], 1u);
            }
        }
        __syncthreads();
        digit_select(hist, need, sh_dg, sh_S1, sh_T, tid);
        thr = (thr << 8) | *sh_dg; need -= (int)*sh_S1;
        C = (K - need) + (int)*sh_T;
        eshift = shift;
    }

    if (C <= CAP) {
        // collect ALL keys with prefix >= thr; sort decides exact order/trim
        for (int it = 0; it < nIter; ++it) {
            int i4 = tid + it * NTHR;
            if (i4 < n4) {
                uint4 kk = k4[i4];
                int i0 = i4 << 2;
                if ((kk.x >> eshift) >= thr) { int p = atomicAdd(sh_gcnt, 1); cand[p] = ((u64)kk.x << 32) | (u32)(0xFFFFFFFFu - (u32)(i0 + 0)); }
                if ((kk.y >> eshift) >= thr) { int p = atomicAdd(sh_gcnt, 1); cand[p] = ((u64)kk.y << 32) | (u32)(0xFFFFFFFFu - (u32)(i0 + 1)); }
                if ((kk.z >> eshift) >= thr) { int p = atomicAdd(sh_gcnt, 1); cand[p] = ((u64)kk.z << 32) | (u32)(0xFFFFFFFFu - (u32)(i0 + 2)); }
                if ((kk.w >> eshift) >= thr) { int p = atomicAdd(sh_gcnt, 1); cand[p] = ((u64)kk.w << 32) | (u32)(0xFFFFFFFFu - (u32)(i0 + 3)); }
            }
        }
        __syncthreads();
        for (int t = C + tid; t < CAP; t += NTHR) cand[t] = 0ull;
    } else {
        // eshift==0, thr is the full 32-bit K-th key; idx-rank trim of exact ties
        for (int i = tid; i < n; i += NTHR) {
            u32 k = keys[i];
            if (k > thr) {
                int p = atomicAdd(sh_gcnt, 1);
                cand[p] = ((u64)k << 32) | (u32)(0xFFFFFFFFu - (u32)i);
            }
        }
        __syncthreads();
        const int G = *sh_gcnt;    // == K - need
        int lo = tid * 32; if (lo > n) lo = n;
        int hi = lo + 32;  if (hi > n) hi = n;
        int lc = 0;
        for (int i = lo; i < hi; ++i) if (keys[i] == thr) ++lc;
        u32* sc_cur = scr; u32* sc_oth = scr + 512;
        sc_cur[tid] = (u32)lc;
        __syncthreads();
        for (int off = 1; off < NTHR; off <<= 1) {
            sc_oth[tid] = sc_cur[tid] + ((tid >= off) ? sc_cur[tid - off] : 0u);
            __syncthreads();
            u32* tmp = sc_cur; sc_cur = sc_oth; sc_oth = tmp;
        }
        int r = (int)sc_cur[tid] - lc;
        for (int i = lo; i < hi; ++i) {
            if (keys[i] == thr) {
                if (r < need) cand[G + r] = ((u64)thr << 32) | (u32)(0xFFFFFFFFu - (u32)i);
                ++r;
            }
        }
        __syncthreads();
        for (int t = K + tid; t < CAP; t += NTHR) cand[t] = 0ull;
    }
    __syncthreads();

    // ---- bitonic sort CAP=512 desc: k<=64 in-wave via shfl_xor, 6 LDS stages only
    u64 v = cand[tid];
#pragma unroll
    for (int k2 = 2; k2 <= 64; k2 <<= 1) {
#pragma unroll
        for (int j = k2 >> 1; j > 0; j >>= 1) {
            u64 p = __shfl_xor(v, j, 64);
            bool takeMax = ((tid & k2) == 0) ^ ((tid & j) != 0);
            v = takeMax ? (v >= p ? v : p) : (v <= p ? v : p);
        }
    }
    for (int k2 = 128; k2 <= CAP; k2 <<= 1) {
        for (int j = k2 >> 1; j >= 64; j >>= 1) {
            __syncthreads();
            cand[tid] = v;
            __syncthreads();
            u64 p = cand[tid ^ j];
            bool takeMax = ((tid & k2) == 0) ^ ((tid & j) != 0);
            v = takeMax ? (v >= p ? v : p) : (v <= p ? v : p);
        }
#pragma unroll
        for (int j = 32; j > 0; j >>= 1) {
            u64 p = __shfl_xor(v, j, 64);
            bool takeMax = ((tid & k2) == 0) ^ ((tid & j) != 0);
            v = takeMax ? (v >= p ? v : p) : (v <= p ? v : p);
        }
    }
    __syncthreads();
    cand[tid] = v;
    __syncthreads();
}

// ---- Stage 1: decode all scores [b][c][n] and clipped boxes float4[b][n] once
__global__ __launch_bounds__(256) void decode_kernel(
    const float* __restrict__ p3, const float* __restrict__ p4, const float* __restrict__ p5,
    const float* __restrict__ a3, const float* __restrict__ a4, const float* __restrict__ a5,
    float* __restrict__ scores, float* __restrict__ boxes)
{
    const int blk = blockIdx.x;
    const int b = blk & 7;
    const int n = ((blk >> 3) << 8) + threadIdx.x;

    const float* base; const float* anc; int logw, nn; float sx;
    if (n < 12288)      { base = p3; anc = a3; logw = 6; nn = n;         sx = 1.2f;  }
    else if (n < 15360) { base = p4; anc = a4; logw = 5; nn = n - 12288; sx = 1.1f;  }
    else                { base = p5; anc = a5; logw = 4; nn = n - 15360; sx = 1.05f; }
    const int W = 1 << logw;
    const int a = nn % 3; const int hw = nn / 3;
    const int w = hw & (W - 1); const int h = hw >> logw;
    const float winv = 1.0f / (float)W;
    const float* rec = base + ((size_t)((b * W + h) * W + w) * 255 + a * 85);

    float tx = rec[0], ty = rec[1], tw = rec[2], th = rec[3], to = rec[4];
    float sobj = sigf(to);
    float cx = (sigf(tx) * sx - 0.5f * (sx - 1.0f) + (float)w) * winv;
    float cy = (sigf(ty) * sx - 0.5f * (sx - 1.0f) + (float)h) * winv;
    float bw = expf(tw) * anc[a * 2 + 0] * (1.0f / 512.0f);   // W*stride == 512 all levels
    float bh = expf(th) * anc[a * 2 + 1] * (1.0f / 512.0f);
    float x1 = cx - 0.5f * bw, x2 = cx + 0.5f * bw;
    float y1 = cy - 0.5f * bh, y2 = cy + 0.5f * bh;
    y1 = fminf(fmaxf(y1, 0.f), 1.f); x1 = fminf(fmaxf(x1, 0.f), 1.f);
    y2 = fminf(fmaxf(y2, 0.f), 1.f); x2 = fminf(fmaxf(x2, 0.f), 1.f);
    float4 bb; bb.x = y1; bb.y = x1; bb.z = y2; bb.w = x2;
    ((float4*)boxes)[b * N_TOT + n] = bb;

    float* sb = scores + (long)b * NCLS * N_TOT + n;
#pragma unroll 8
    for (int cc = 0; cc < NCLS; ++cc)
        sb[(long)cc * N_TOT] = sigf(rec[5 + cc]) * sobj;
}

// ---- Stage 2 (fused path): per (image,class) top-400 -> NMS -> compact
__global__ __launch_bounds__(NTHR, 8) void topk_nms_fused(
    const float* __restrict__ scores, const float* __restrict__ boxes,
    float* __restrict__ ksc, float* __restrict__ kbox)
{
    __shared__ alignas(16) u64 cand[CAP];                // 4096 B
    __shared__ u32 hist[260];                            // 1040 B
    __shared__ u32 sh_dg, sh_S1, sh_T;
    __shared__ int sh_gcnt;
    __shared__ alignas(16) u64 sup[PRE_K * 7];           // 22400 B (also trim scratch)
    __shared__ float by1[448], bx1[448], by2[448], bx2[448], bar[448];  // 8960 B
    __shared__ u64 keepw[7];
    __shared__ int wpre[8];
    __shared__ int sh_ncnt;

    const int tid = threadIdx.x;
    const int wv = tid >> 6;
    const int lane = tid & 63;
    const int b = blockIdx.x & 7;     // all 80 class-blocks of an image on one XCD
    const int c = blockIdx.x >> 3;

    const u32* keys = (const u32*)(scores + (long)(b * NCLS + c) * N_TOT);

    // ---- pass-1 histogram: wave-aggregated atomics (digits are concentrated)
    if (tid < 260) hist[tid] = 0u;
    if (tid == 0) sh_gcnt = 0;
    __syncthreads();
    const uint4* k4 = (const uint4*)keys;
#pragma unroll
    for (int it = 0; it < 8; ++it) {
        int i4 = tid + it * NTHR;
        bool v = i4 < (N_TOT >> 2);
        u32 d0 = 0, d1 = 0, d2 = 0, d3 = 0;
        if (v) {
            uint4 kk = k4[i4];
            d0 = kk.x >> 24; d1 = kk.y >> 24; d2 = kk.z >> 24; d3 = kk.w >> 24;
        }
        hist_agg(hist, d0, v, lane);
        hist_agg(hist, d1, v, lane);
        hist_agg(hist, d2, v, lane);
        hist_agg(hist, d3, v, lane);
    }
    __syncthreads();

    radix_topk_sort(keys, N_TOT, PRE_K, cand, hist, (u32*)sup,
                    &sh_dg, &sh_S1, &sh_T, &sh_gcnt, tid);

    for (int t = tid; t < PRE_K * 7; t += NTHR) sup[t] = 0ull;

    // gather top-400 boxes from table (SoA, padded to 448)
    const float4* btab = (const float4*)boxes;
    for (int t = tid; t < 448; t += NTHR) {
        float y1 = 0.f, x1 = 0.f, y2 = 0.f, x2 = 0.f;
        if (t < PRE_K) {
            u64 key = cand[t];
            if ((key >> 32) != 0ull) {
                int idx = (int)(0xFFFFFFFFu - (u32)(key & 0xFFFFFFFFull));
                float4 bb = btab[b * N_TOT + idx];
                y1 = bb.x; x1 = bb.y; y2 = bb.z; x2 = bb.w;
            }
        }
        by1[t] = y1; bx1[t] = x1; by2[t] = y2; bx2[t] = x2;
        bar[t] = (y2 - y1) * (x2 - x1);
    }
    __syncthreads();

    // suppression bitmask rows via ballot (upper triangle), 8 waves
    for (int row = wv; row < PRE_K; row += 8) {
        float ry1 = by1[row], rx1 = bx1[row], ry2 = by2[row], rx2 = bx2[row], ra = bar[row];
        int c0 = (row + 1) >> 6;
        for (int cw = c0; cw < 7; ++cw) {
            int j = (cw << 6) + lane;
            bool o = false;
            if (j > row && j < PRE_K) {
                float ty = fmaxf(ry1, by1[j]);
                float tx = fmaxf(rx1, bx1[j]);
                float by = fminf(ry2, by2[j]);
                float rx = fminf(rx2, bx2[j]);
                float hh = fmaxf(by - ty, 0.f);
                float ww = fmaxf(rx - tx, 0.f);
                float inter = hh * ww;
                float uni = ra + bar[j] - inter;
                o = (inter / fmaxf(uni, 1e-9f)) > NMS_T;
            }
            u64 m = __ballot(o);
            if (lane == 0) sup[row * 7 + cw] = m;
        }
    }
    __syncthreads();

    // greedy suppression: single wave, keep bits in registers, prefetched rows
    if (tid < 64) {
        u64 kw = (tid < 6) ? ~0ull : ((tid == 6) ? 0xFFFFull : 0ull);
        u64 s_cur = (tid < 7) ? sup[tid] : 0ull;
        for (int i = 0; i < PRE_K; ++i) {
            u64 s_next = (tid < 7 && (i + 1) < PRE_K) ? sup[(i + 1) * 7 + tid] : 0ull;
            u64 kwv = __shfl(kw, i >> 6);
            if ((kwv >> (i & 63)) & 1ull) kw &= ~s_cur;
            s_cur = s_next;
        }
        if (tid < 7) keepw[tid] = kw;
    }
    __syncthreads();

    if (tid == 0) {
        int acc = 0;
        for (int w = 0; w < 7; ++w) { wpre[w] = acc; acc += (int)__popcll(keepw[w]); }
        sh_ncnt = acc < KEEP_CAP ? acc : KEEP_CAP;
    }
    __syncthreads();

    const int blk_out = b * NCLS + c;
    float* osc = ksc + (long)blk_out * KEEP_CAP;
    float* obx = kbox + (long)blk_out * KEEP_CAP * 4;
    for (int t = tid; t < PRE_K; t += NTHR) {
        int w = t >> 6, bb = t & 63;
        u64 kwv = keepw[w];
        if ((kwv >> bb) & 1ull) {
            int pos = wpre[w] + (int)__popcll(kwv & ((1ull << bb) - 1ull));
            if (pos < KEEP_CAP) {
                osc[pos] = __uint_as_float((u32)(cand[t] >> 32));
                obx[pos * 4 + 0] = by1[t]; obx[pos * 4 + 1] = bx1[t];
                obx[pos * 4 + 2] = by2[t]; obx[pos * 4 + 3] = bx2[t];
            }
        }
    }
    for (int t = sh_ncnt + tid; t < KEEP_CAP; t += NTHR) {
        osc[t] = 0.0f;
        obx[t * 4 + 0] = 0.f; obx[t * 4 + 1] = 0.f;
        obx[t * 4 + 2] = 0.f; obx[t * 4 + 3] = 0.f;
    }
}

// ---- Fallback monolithic stage-2 if ws too small for score table
__global__ __launch_bounds__(NTHR, 4) void topk_nms_mono(
    const float* __restrict__ p3, const float* __restrict__ p4, const float* __restrict__ p5,
    const float* __restrict__ a3, const float* __restrict__ a4, const float* __restrict__ a5,
    float* __restrict__ ksc, float* __restrict__ kbox)
{
    __shared__ alignas(16) u32 skey[N_TOT];
    __shared__ alignas(16) u64 cand[CAP];
    __shared__ u32 hist[260];
    __shared__ u32 scr[1024];
    __shared__ u32 sh_dg, sh_S1, sh_T;
    __shared__ int sh_gcnt;
    __shared__ u64 keepw[7];
    __shared__ int wpre[8];
    __shared__ int sh_ncnt;

    const int tid = threadIdx.x;
    const int wv = tid >> 6;
    const int lane = tid & 63;
    const int b = blockIdx.x & 7;
    const int c = blockIdx.x >> 3;

    if (tid < 260) hist[tid] = 0u;
    if (tid == 0) sh_gcnt = 0;
    __syncthreads();
    for (int i = tid; i < N_TOT; i += NTHR) {
        const float* base; int H, W, n;
        if (i < 12288)      { base = p3; H = 64; W = 64; n = i; }
        else if (i < 15360) { base = p4; H = 32; W = 32; n = i - 12288; }
        else                { base = p5; H = 16; W = 16; n = i - 15360; }
        int a = n % 3; int hw = n / 3; int w = hw % W; int h = hw / W;
        const float* rec = base + (((b * H + h) * W + w) * 255 + a * 85);
        float s = sigf(rec[5 + c]) * sigf(rec[4]);
        u32 k = __float_as_uint(s);
        skey[i] = k;
        hist_agg(hist, k >> 24, true, lane);
    }
    __syncthreads();

    radix_topk_sort(skey, N_TOT, PRE_K, cand, hist, scr,
                    &sh_dg, &sh_S1, &sh_T, &sh_gcnt, tid);

    u64* sup  = (u64*)skey;
    float* by1 = (float*)(skey + 5600);
    float* bx1 = by1 + 448;
    float* by2 = bx1 + 448;
    float* bx2 = by2 + 448;
    float* bar = bx2 + 448;

    for (int t = tid; t < PRE_K * 7; t += NTHR) sup[t] = 0ull;

    for (int t = tid; t < 448; t += NTHR) {
        float y1 = 0.f, x1 = 0.f, y2 = 0.f, x2 = 0.f;
        if (t < PRE_K) {
            u64 key = cand[t];
            if ((key >> 32) != 0ull) {
                int idx = (int)(0xFFFFFFFFu - (u32)(key & 0xFFFFFFFFull));
                const float* base; const float* anc; int H, W, n; float sx, strd;
                if (idx < 12288)      { base = p3; anc = a3; H = 64; W = 64; n = idx;         sx = 1.2f;  strd = 8.f;  }
                else if (idx < 15360) { base = p4; anc = a4; H = 32; W = 32; n = idx - 12288; sx = 1.1f;  strd = 16.f; }
                else                  { base = p5; anc = a5; H = 16; W = 16; n = idx - 15360; sx = 1.05f; strd = 32.f; }
                int a = n % 3; int hw = n / 3; int w = hw % W; int h = hw / W;
                const float* rec = base + (((b * H + h) * W + w) * 255 + a * 85);
                float tx = rec[0], ty = rec[1], tw = rec[2], th = rec[3];
                float cx = (sigf(tx) * sx - 0.5f * (sx - 1.0f) + (float)w) / (float)W;
                float cy = (sigf(ty) * sx - 0.5f * (sx - 1.0f) + (float)h) / (float)H;
                float bw = expf(tw) * anc[a * 2 + 0] / ((float)W * strd);
                float bh = expf(th) * anc[a * 2 + 1] / ((float)H * strd);
                x1 = cx - 0.5f * bw; x2 = cx + 0.5f * bw;
                y1 = cy - 0.5f * bh; y2 = cy + 0.5f * bh;
                y1 = fminf(fmaxf(y1, 0.f), 1.f); x1 = fminf(fmaxf(x1, 0.f), 1.f);
                y2 = fminf(fmaxf(y2, 0.f), 1.f); x2 = fminf(fmaxf(x2, 0.f), 1.f);
            }
        }
        by1[t] = y1; bx1[t] = x1; by2[t] = y2; bx2[t] = x2;
        bar[t] = (y2 - y1) * (x2 - x1);
    }
    __syncthreads();

    for (int row = wv; row < PRE_K; row += 8) {
        float ry1 = by1[row], rx1 = bx1[row], ry2 = by2[row], rx2 = bx2[row], ra = bar[row];
        int c0 = (row + 1) >> 6;
        for (int cw = c0; cw < 7; ++cw) {
            int j = (cw << 6) + lane;
            bool o = false;
            if (j > row && j < PRE_K) {
                float ty = fmaxf(ry1, by1[j]);
                float tx = fmaxf(rx1, bx1[j]);
                float by = fminf(ry2, by2[j]);
                float rx = fminf(rx2, bx2[j]);
                float hh = fmaxf(by - ty, 0.f);
                float ww = fmaxf(rx - tx, 0.f);
                float inter = hh * ww;
                float uni = ra + bar[j] - inter;
                o = (inter / fmaxf(uni, 1e-9f)) > NMS_T;
            }
            u64 m = __ballot(o);
            if (lane == 0) sup[row * 7 + cw] = m;
        }
    }
    __syncthreads();

    if (tid < 64) {
        u64 kw = (tid < 6) ? ~0ull : ((tid == 6) ? 0xFFFFull : 0ull);
        u64 s_cur = (tid < 7) ? sup[tid] : 0ull;
        for (int i = 0; i < PRE_K; ++i) {
            u64 s_next = (tid < 7 && (i + 1) < PRE_K) ? sup[(i + 1) * 7 + tid] : 0ull;
            u64 kwv = __shfl(kw, i >> 6);
            if ((kwv >> (i & 63)) & 1ull) kw &= ~s_cur;
            s_cur = s_next;
        }
        if (tid < 7) keepw[tid] = kw;
    }
    __syncthreads();

    if (tid == 0) {
        int acc = 0;
        for (int w = 0; w < 7; ++w) { wpre[w] = acc; acc += (int)__popcll(keepw[w]); }
        sh_ncnt = acc < KEEP_CAP ? acc : KEEP_CAP;
    }
    __syncthreads();

    const int blk_out = b * NCLS + c;
    float* osc = ksc + (long)blk_out * KEEP_CAP;
    float* obx = kbox + (long)blk_out * KEEP_CAP * 4;
    for (int t = tid; t < PRE_K; t += NTHR) {
        int w = t >> 6, bb = t & 63;
        u64 kwv = keepw[w];
        if ((kwv >> bb) & 1ull) {
            int pos = wpre[w] + (int)__popcll(kwv & ((1ull << bb) - 1ull));
            if (pos < KEEP_CAP) {
                osc[pos] = __uint_as_float((u32)(cand[t] >> 32));
                obx[pos * 4 + 0] = by1[t]; obx[pos * 4 + 1] = bx1[t];
                obx[pos * 4 + 2] = by2[t]; obx[pos * 4 + 3] = bx2[t];
            }
        }
    }
    for (int t = sh_ncnt + tid; t < KEEP_CAP; t += NTHR) {
        osc[t] = 0.0f;
        obx[t * 4 + 0] = 0.f; obx[t * 4 + 1] = 0.f;
        obx[t * 4 + 2] = 0.f; obx[t * 4 + 3] = 0.f;
    }
}

// ---- Stage 3: per image top-200 over 16000 compacted candidates -> outputs
__global__ __launch_bounds__(NTHR) void final_topk_kernel(
    const float* __restrict__ ksc, const float* __restrict__ kbox,
    float* __restrict__ out)
{
    __shared__ alignas(16) u64 cand[CAP];
    __shared__ u32 hist[260];
    __shared__ u32 scr[1024];
    __shared__ u32 sh_dg, sh_S1, sh_T;
    __shared__ int sh_gcnt;

    const int tid = threadIdx.x;
    const int lane = tid & 63;
    const int b = blockIdx.x;
    const u32* keys = (const u32*)(ksc + (long)b * M_FIN);

    if (tid < 260) hist[tid] = 0u;
    if (tid == 0) sh_gcnt = 0;
    __syncthreads();
    const uint4* k4 = (const uint4*)keys;
#pragma unroll
    for (int it = 0; it < 8; ++it) {
        int i4 = tid + it * NTHR;
        bool v = i4 < (M_FIN >> 2);
        u32 d0 = 0, d1 = 0, d2 = 0, d3 = 0;
        if (v) {
            uint4 kk = k4[i4];
            d0 = kk.x >> 24; d1 = kk.y >> 24; d2 = kk.z >> 24; d3 = kk.w >> 24;
        }
        hist_agg(hist, d0, v, lane);
        hist_agg(hist, d1, v, lane);
        hist_agg(hist, d2, v, lane);
        hist_agg(hist, d3, v, lane);
    }
    __syncthreads();

    radix_topk_sort(keys, M_FIN, MAX_BOXES, cand, hist, scr,
                    &sh_dg, &sh_S1, &sh_T, &sh_gcnt, tid);

    float* obb = out;                         // (8,200,4)
    float* ocf = out + 8 * MAX_BOXES * 4;     // (8,200)
    float* ocl = ocf + 8 * MAX_BOXES;         // (8,200)
    float* onm = ocl + 8 * MAX_BOXES;         // (8,)

    float s = 0.f;
    if (tid < MAX_BOXES) {
        u64 key = cand[tid];
        s = __uint_as_float((u32)(key >> 32));
        float y1 = 0.f, x1 = 0.f, y2 = 0.f, x2 = 0.f, cid = 0.f;
        if (s > 0.0f) {
            int i = (int)(0xFFFFFFFFu - (u32)(key & 0xFFFFFFFFull));
            int cc = i / KEEP_CAP, j = i % KEEP_CAP;
            const float* bb = kbox + (((long)b * NCLS + cc) * KEEP_CAP + j) * 4;
            y1 = bb[0]; x1 = bb[1]; y2 = bb[2]; x2 = bb[3];
            cid = (float)cc;
        }
        long o = (long)b * MAX_BOXES + tid;
        obb[o * 4 + 0] = y1; obb[o * 4 + 1] = x1; obb[o * 4 + 2] = y2; obb[o * 4 + 3] = x2;
        ocf[o] = s; ocl[o] = cid;
    }
    int cnt = __syncthreads_count(tid < MAX_BOXES && s > 0.0f);
    if (tid == 0) onm[b] = (float)cnt;
}

extern "C" void kernel_launch(void* const* d_in, const int* in_sizes, int n_in,
                              void* d_out, int out_size, void* d_ws, size_t ws_size,
                              hipStream_t stream) {
    const float* p3 = (const float*)d_in[0];
    const float* p4 = (const float*)d_in[1];
    const float* p5 = (const float*)d_in[2];
    const float* a3 = (const float*)d_in[3];
    const float* a4 = (const float*)d_in[4];
    const float* a5 = (const float*)d_in[5];
    float* out = (float*)d_out;

    const size_t score_bytes = (size_t)8 * NCLS * N_TOT * 4;      // 41,287,680
    const size_t boxes_bytes = (size_t)8 * N_TOT * 16;            //  2,064,384
    const size_t ksc_bytes   = (size_t)8 * NCLS * KEEP_CAP * 4;   //    512,000
    const size_t kbox_bytes  = (size_t)8 * NCLS * KEEP_CAP * 16;  //  2,048,000

    if (ws_size >= score_bytes + boxes_bytes + ksc_bytes + kbox_bytes) {
        float* scores = (float*)d_ws;
        float* boxes  = (float*)((char*)d_ws + score_bytes);
        float* ksc    = (float*)((char*)d_ws + score_bytes + boxes_bytes);
        float* kbox   = (float*)((char*)d_ws + score_bytes + boxes_bytes + ksc_bytes);
        decode_kernel<<<504, 256, 0, stream>>>(p3, p4, p5, a3, a4, a5, scores, boxes);
        topk_nms_fused<<<8 * NCLS, NTHR, 0, stream>>>(scores, boxes, ksc, kbox);
        final_topk_kernel<<<8, NTHR, 0, stream>>>(ksc, kbox, out);
    } else {
        float* ksc  = (float*)d_ws;
        float* kbox = ksc + 8 * NCLS * KEEP_CAP;
        topk_nms_mono<<<8 * NCLS, NTHR, 0, stream>>>(p3, p4, p5, a3, a4, a5, ksc, kbox);
        final_topk_kernel<<<8, NTHR, 0, stream>>>(ksc, kbox, out);
    }
}